// Round 7
// baseline (819.083 us; speedup 1.0000x reference)
//
#include <hip/hip_runtime.h>
#include <hip/hip_bf16.h>
#include <math.h>

#define BB 8
#define TT 4096
#define HHD 128
#define NBK 6
#define KNN 20
#define BT (BB*TT)

typedef __attribute__((ext_vector_type(8))) short bf16x8;
typedef __attribute__((ext_vector_type(4))) float f32x4;

__device__ __forceinline__ float b2f(unsigned short u){
  return __uint_as_float(((unsigned int)u) << 16);
}
__device__ __forceinline__ unsigned short f2b(float f){
  unsigned int x = __float_as_uint(f);
  unsigned int r = (x + 0x7fffu + ((x >> 16) & 1u)) >> 16;   // RTNE
  return (unsigned short)r;
}
// dtype-agnostic parameter load: f32m=1 -> buffer is float32, else bf16
__device__ __forceinline__ float ldp(const void* base, int i, int f32m){
  return f32m ? ((const float*)base)[i] : b2f(((const unsigned short*)base)[i]);
}
__device__ __forceinline__ float lo2f(unsigned int u){ return __uint_as_float(u << 16); }
__device__ __forceinline__ float hi2f(unsigned int u){ return __uint_as_float(u & 0xffff0000u); }
__device__ __forceinline__ unsigned int relu2(unsigned int u){
  unsigned int s = u & 0x80008000u;
  unsigned int m = s | (s - (s >> 15));
  return u & ~m;
}
__device__ __forceinline__ bf16x8 relu8(bf16x8 x){
  union { bf16x8 v; unsigned int u[4]; } t; t.v = x;
  t.u[0] = relu2(t.u[0]); t.u[1] = relu2(t.u[1]);
  t.u[2] = relu2(t.u[2]); t.u[3] = relu2(t.u[3]);
  return t.v;
}

// ---------------- dtype detector ----------------
__global__ void k_detect(const unsigned short* __restrict__ wpos_raw, int* __restrict__ flag){
  if (threadIdx.x == 0 && blockIdx.x == 0) {
    int cnt = 0;
    for (int i = 0; i < 384; ++i) {
      unsigned int e = (wpos_raw[i] >> 7) & 0xFFu;
      if (e >= 0x90u) cnt++;
    }
    *flag = (cnt > 10) ? 1 : 0;
  }
}

// ---------------- prep: p -> float4 (x,y,z,|p|^2) ----------------
__global__ __launch_bounds__(256) void k_prep_points(const void* __restrict__ p,
                                                     const int* __restrict__ flagp,
                                                     float4* __restrict__ pf4){
  int r = blockIdx.x*256 + threadIdx.x;
  if (r >= BT) return;
  int f32m = *flagp;
  float x = ldp(p, r*3+0, f32m), y = ldp(p, r*3+1, f32m), z = ldp(p, r*3+2, f32m);
  float sq = __fadd_rn(__fadd_rn(__fmul_rn(x,x), __fmul_rn(y,y)), __fmul_rn(z,z));
  pf4[r] = make_float4(x, y, z, sq);
}

// ---------------- net0 = p @ W_pos + b_pos  (bf16 out) ----------------
__global__ __launch_bounds__(256) void k_net0(const float4* __restrict__ pf4,
                                              const void* __restrict__ Wpos,
                                              const void* __restrict__ bpos,
                                              const int* __restrict__ flagp,
                                              unsigned short* __restrict__ netA){
  int t = blockIdx.x*256 + threadIdx.x;   // over BT*128
  int f32m = *flagp;
  int c = t & 127, r = t >> 7;
  float4 q = pf4[r];
  float v = ldp(bpos, c, f32m);
  v = fmaf(q.x, ldp(Wpos, c,       f32m), v);
  v = fmaf(q.y, ldp(Wpos, 128 + c, f32m), v);
  v = fmaf(q.z, ldp(Wpos, 256 + c, f32m), v);
  netA[t] = f2b(v);
}

// ---------------- transpose all weights to [N][K] bf16 ----------------
// layout in wT (shorts): W0T 6*32768 | W1T 6*16384 | WsT 6*32768 | WoT 6*16384 | WcT 16384
__global__ __launch_bounds__(256) void k_transpose(const void* __restrict__ W0,
                                                   const void* __restrict__ W1,
                                                   const void* __restrict__ Ws,
                                                   const void* __restrict__ Wo,
                                                   const void* __restrict__ Wc,
                                                   const int* __restrict__ flagp,
                                                   unsigned short* __restrict__ wT){
  int t = blockIdx.x*256 + threadIdx.x;
  int f32m = *flagp;
  if (t < 196608) {                    // W0T: per block [128][256]
    int i = t >> 15; int rem = t & 32767; int n = rem >> 8; int k = rem & 255;
    wT[t] = f2b(ldp(W0, i*32768 + k*128 + n, f32m));
  } else if (t < 294912) {             // W1T: [128][128]
    int u = t - 196608; int i = u >> 14; int rem = u & 16383; int n = rem >> 7; int k = rem & 127;
    wT[t] = f2b(ldp(W1, i*16384 + k*128 + n, f32m));
  } else if (t < 491520) {             // WsT: [128][256]
    int u = t - 294912; int i = u >> 15; int rem = u & 32767; int n = rem >> 8; int k = rem & 255;
    wT[t] = f2b(ldp(Ws, i*32768 + k*128 + n, f32m));
  } else if (t < 589824) {             // WoT: [128][128]
    int u = t - 491520; int i = u >> 14; int rem = u & 16383; int n = rem >> 7; int k = rem & 127;
    wT[t] = f2b(ldp(Wo, i*16384 + k*128 + n, f32m));
  } else if (t < 606208) {             // WcT: [128][128]
    int u = t - 589824; int n = u >> 7; int k = u & 127;
    wT[t] = f2b(ldp(Wc, k*128 + n, f32m));
  }
}

// sorted ascending insert into (ld,li)[20], strict '<' keeps earliest index on ties
#define INS(act, dv, iv) do { bool A_ = (act); float D_ = (dv); int I_ = (iv);        \
  _Pragma("unroll")                                                                    \
  for (int j = 19; j >= 1; --j) {                                                      \
    bool cj = A_ && (D_ < ld[j]); bool cm = A_ && (D_ < ld[j-1]);                      \
    ld[j] = cj ? (cm ? ld[j-1] : D_) : ld[j];                                          \
    li[j] = cj ? (cm ? li[j-1] : I_) : li[j];                                          \
  }                                                                                    \
  { bool c0 = A_ && (D_ < ld[0]); ld[0] = c0 ? D_ : ld[0]; li[0] = c0 ? I_ : li[0]; } \
} while(0)

// ---------------- KNN: 4 waves/query-group, partitioned candidates ----------------
// (round-4 proven version, unchanged)
__global__ __launch_bounds__(256) void k_knn(const float4* __restrict__ pf4,
                                             const void* __restrict__ Wc,
                                             const void* __restrict__ bc,
                                             const int* __restrict__ flagp,
                                             unsigned short* __restrict__ idx16,
                                             unsigned short* __restrict__ wsoftb){
  __shared__ char smem[40960];
  float4* tile = (float4*)smem;                 // [4][256] float4 = 16 KB (scan phase)
  float*  lsd  = (float*)smem;                  // [256][20] = 20 KB (merge phase)
  int*    lsi  = (int*)(smem + 20480);          // [256][20] = 20 KB

  int tid  = threadIdx.x;
  int part = tid >> 6, lane = tid & 63;
  int rq   = blockIdx.x*64 + lane;              // query row (512 blocks x 64)
  int b    = rq >> 12;
  int f32m = *flagp;
  float4 q = pf4[rq];

  float ld[20]; int li[20];
  #pragma unroll
  for (int j = 0; j < 20; ++j) { ld[j] = 3.0e38f; li[j] = 0; }
  float thresh = 3.0e38f;
  float bd0=0.f,bd1=0.f,bd2=0.f,bd3=0.f; int bi0=0,bi1=0,bi2=0,bi3=0; int cnt=0;

  for (int ch = 0; ch < 4; ++ch) {
    __syncthreads();
    {
      const float4* src = pf4 + (b << 12) + part*1024 + ch*256;
      tile[part*256 + lane      ] = src[lane      ];
      tile[part*256 + lane +  64] = src[lane +  64];
      tile[part*256 + lane + 128] = src[lane + 128];
      tile[part*256 + lane + 192] = src[lane + 192];
    }
    __syncthreads();
    int baseI = part*1024 + ch*256;
    for (int j = 0; j < 256; ++j) {
      float4 pt = tile[part*256 + j];
      float dot = __fadd_rn(__fadd_rn(__fmul_rn(q.x,pt.x), __fmul_rn(q.y,pt.y)),
                            __fmul_rn(q.z,pt.z));
      float d2  = __fsub_rn(__fadd_rn(q.w, pt.w), __fmul_rn(2.0f, dot));
      bool take = d2 < thresh;       // thresh is upper bound of true 20th-best: never drops a keeper
      int  gi   = baseI + j;
      bool t0 = take && (cnt == 0); bd0 = t0 ? d2 : bd0; bi0 = t0 ? gi : bi0;
      bool t1 = take && (cnt == 1); bd1 = t1 ? d2 : bd1; bi1 = t1 ? gi : bi1;
      bool t2 = take && (cnt == 2); bd2 = t2 ? d2 : bd2; bi2 = t2 ? gi : bi2;
      bool t3 = take && (cnt == 3); bd3 = t3 ? d2 : bd3; bi3 = t3 ? gi : bi3;
      cnt += take ? 1 : 0;
      if (__ballot(cnt >= 4)) {      // wave-uniform branch
        INS(cnt > 0, bd0, bi0); INS(cnt > 1, bd1, bi1);
        INS(cnt > 2, bd2, bi2); INS(cnt > 3, bd3, bi3);
        cnt = 0; thresh = ld[19];
      }
    }
  }
  INS(cnt > 0, bd0, bi0); INS(cnt > 1, bd1, bi1);
  INS(cnt > 2, bd2, bi2); INS(cnt > 3, bd3, bi3);

  __syncthreads();                   // scan done; tile region reused as lsd/lsi
  #pragma unroll
  for (int j = 0; j < 20; ++j) { lsd[tid*20 + j] = ld[j]; lsi[tid*20 + j] = li[j]; }
  __syncthreads();

  if (tid < 64) {                    // lane q of wave 0 merges query q's 4 lists
    int p0 = tid*20, p1 = (64+tid)*20, p2 = (128+tid)*20, p3 = (192+tid)*20;
    int i0=0, i1=0, i2=0, i3=0;
    float dis[20]; int outi[20];
    #pragma unroll 4
    for (int o = 0; o < 20; ++o) {
      float d0 = lsd[p0+i0], d1 = lsd[p1+i1], d2v = lsd[p2+i2], d3 = lsd[p3+i3];
      float bd = d0; int sel = 0;
      if (d1  < bd) { bd = d1;  sel = 1; }    // strict <: lowest partition wins ties
      if (d2v < bd) { bd = d2v; sel = 2; }
      if (d3  < bd) { bd = d3;  sel = 3; }
      int bi = (sel==0) ? lsi[p0+i0] : (sel==1) ? lsi[p1+i1] : (sel==2) ? lsi[p2+i2] : lsi[p3+i3];
      i0 += (sel==0); i1 += (sel==1); i2 += (sel==2); i3 += (sel==3);
      dis[o] = sqrtf(fmaxf(bd, 1e-12f));
      outi[o] = bi;
    }
    // ---- fused attention softmax weights, all 6 blocks ----
    float nx[20], ny[20], nz[20];
    #pragma unroll 4
    for (int k = 0; k < 20; ++k) {
      idx16[rq*20 + k] = (unsigned short)outi[k];
      float4 pp = pf4[(b << 12) + outi[k]];
      nx[k] = pp.x; ny[k] = pp.y; nz[k] = pp.z;
    }
    for (int i = 0; i < NBK; ++i) {
      float w0 = ldp(Wc,i*7+0,f32m), w1 = ldp(Wc,i*7+1,f32m), w2 = ldp(Wc,i*7+2,f32m);
      float w3 = ldp(Wc,i*7+3,f32m), w4 = ldp(Wc,i*7+4,f32m), w5 = ldp(Wc,i*7+5,f32m);
      float w6 = ldp(Wc,i*7+6,f32m);
      float bci = ldp(bc,i,f32m);
      float s[20]; float mx = -3.0e38f;
      #pragma unroll
      for (int k = 0; k < 20; ++k) {
        float v = bci;
        v = fmaf(dis[k], w0, v);
        v = fmaf(nx[k], w1, v); v = fmaf(ny[k], w2, v); v = fmaf(nz[k], w3, v);
        v = fmaf(q.x, w4, v);  v = fmaf(q.y, w5, v);  v = fmaf(q.z, w6, v);
        s[k] = v; mx = fmaxf(mx, v);
      }
      float sum = 0.f;
      #pragma unroll
      for (int k = 0; k < 20; ++k) { float e = __expf(s[k] - mx); s[k] = e; sum += e; }
      float inv = 1.0f / sum;
      #pragma unroll
      for (int k = 0; k < 20; ++k) wsoftb[(rq*6 + i)*20 + k] = f2b(s[k]*inv);
    }
  }
}

// ---------------- one resnet block (fused gather+attention+GEMMs) ----------------
// Occupancy restructure: 2048 blocks x 16 rows; 4 waves share one 16-row tile,
// each wave owns 2 of 8 col-tiles (32 cols). LDS 8.7 KB/block -> ~6-8 blocks/CU
// resident so barrier stalls overlap across blocks.
__global__ __launch_bounds__(256) void k_block(const unsigned short* __restrict__ netIn,
                                               unsigned short* __restrict__ netOut,
                                               const unsigned short* __restrict__ idx16,
                                               const unsigned short* __restrict__ wsoftb,
                                               const unsigned short* __restrict__ wT,
                                               const void* __restrict__ b0s,
                                               const void* __restrict__ b1s,
                                               const void* __restrict__ bos,
                                               const int* __restrict__ flagp,
                                               int iblk, int hasResid){
  __shared__ unsigned short ldsA[16*136];
  __shared__ unsigned short ldsH[16*136];
  int tid = threadIdx.x;
  int f32m = *flagp;
  int w = tid >> 6, lane = tid & 63;
  int b  = blockIdx.x & 7;   // XCD swizzle: gathers stay within one batch's net
  int r0 = (b << 12) + ((blockIdx.x >> 3) << 4);
  const unsigned short* W0T = wT + iblk*32768;
  const unsigned short* W1T = wT + 196608 + iblk*16384;
  const unsigned short* WsT = wT + 294912 + iblk*32768;
  const unsigned short* WoT = wT + 491520 + iblk*16384;
  int m = lane & 15, qd = lane >> 4;

  // ---- stage 1: attsum[r][g*8..g*8+8] = sum_k w * netIn[idx_k] ----
  {
    int r = tid & 15, g = tid >> 4;       // 16 rows x 16 col-groups of 8
    int grow = r0 + r;
    float acc[8];
    #pragma unroll
    for (int j = 0; j < 8; ++j) acc[j] = 0.f;
    #pragma unroll 4
    for (int k = 0; k < 20; ++k) {
      int nb = idx16[grow*20 + k] & 4095;
      float wk = b2f(wsoftb[(grow*6 + iblk)*20 + k]);
      uint4 uu = *(const uint4*)(netIn + ((b << 12) + nb)*128 + g*8);
      acc[0] = fmaf(wk, lo2f(uu.x), acc[0]);
      acc[1] = fmaf(wk, hi2f(uu.x), acc[1]);
      acc[2] = fmaf(wk, lo2f(uu.y), acc[2]);
      acc[3] = fmaf(wk, hi2f(uu.y), acc[3]);
      acc[4] = fmaf(wk, lo2f(uu.z), acc[4]);
      acc[5] = fmaf(wk, hi2f(uu.z), acc[5]);
      acc[6] = fmaf(wk, lo2f(uu.w), acc[6]);
      acc[7] = fmaf(wk, hi2f(uu.w), acc[7]);
    }
    #pragma unroll
    for (int j = 0; j < 4; ++j) {
      unsigned int pr = ((unsigned int)f2b(acc[2*j+1]) << 16) | (unsigned int)f2b(acc[2*j]);
      *(unsigned int*)(ldsH + r*136 + g*8 + 2*j) = pr;
    }
  }
  __syncthreads();

  // ---- stage 2: att = attsum @ Wo^T + bo -> ldsA (2 col-tiles per wave) ----
  {
    bf16x8 asf[4];
    #pragma unroll
    for (int ks = 0; ks < 4; ++ks)
      asf[ks] = *(const bf16x8*)(ldsH + m*136 + ks*32 + qd*8);
    f32x4 acc2[2];
    #pragma unroll
    for (int i = 0; i < 2; ++i) { f32x4 z = {0.f,0.f,0.f,0.f}; acc2[i] = z; }
    #pragma unroll
    for (int i = 0; i < 2; ++i) {
      int cti = w*2 + i;
      const unsigned short* bp = WoT + (cti*16 + m)*128 + qd*8;
      #pragma unroll
      for (int ks = 0; ks < 4; ++ks)
        acc2[i] = __builtin_amdgcn_mfma_f32_16x16x32_bf16(asf[ks], *(const bf16x8*)(bp + ks*32), acc2[i], 0, 0, 0);
    }
    #pragma unroll
    for (int i = 0; i < 2; ++i) {
      int col = (w*2 + i)*16 + m;
      float bo = ldp(bos, iblk*128 + col, f32m);
      #pragma unroll
      for (int rr = 0; rr < 4; ++rr)
        ldsA[(qd*4 + rr)*136 + col] = f2b(acc2[i][rr] + bo);
    }
  }
  __syncthreads();

  // ---- stage 3: h = relu(net)@W0a + relu(att)@W0b + b0; relu(h) -> ldsH ----
  bf16x8 nf[4], af[4];
  {
    const unsigned short* nrow = netIn + (r0 + m)*128;
    #pragma unroll
    for (int ks = 0; ks < 4; ++ks) nf[ks] = *(const bf16x8*)(nrow + ks*32 + qd*8);
    #pragma unroll
    for (int ks = 0; ks < 4; ++ks) af[ks] = *(const bf16x8*)(ldsA + m*136 + ks*32 + qd*8);
    bf16x8 rnf[4], raf[4];
    #pragma unroll
    for (int ks = 0; ks < 4; ++ks) { rnf[ks] = relu8(nf[ks]); raf[ks] = relu8(af[ks]); }
    f32x4 acc3[2];
    #pragma unroll
    for (int i = 0; i < 2; ++i) { f32x4 z = {0.f,0.f,0.f,0.f}; acc3[i] = z; }
    #pragma unroll
    for (int i = 0; i < 2; ++i) {
      int cti = w*2 + i;
      const unsigned short* bp = W0T + (cti*16 + m)*256 + qd*8;
      #pragma unroll
      for (int ks = 0; ks < 4; ++ks)
        acc3[i] = __builtin_amdgcn_mfma_f32_16x16x32_bf16(rnf[ks], *(const bf16x8*)(bp + ks*32), acc3[i], 0, 0, 0);
      #pragma unroll
      for (int ks = 0; ks < 4; ++ks)
        acc3[i] = __builtin_amdgcn_mfma_f32_16x16x32_bf16(raf[ks], *(const bf16x8*)(bp + 128 + ks*32), acc3[i], 0, 0, 0);
    }
    __syncthreads();   // ensure all stage-2 ldsH readers (asf) are done before overwrite
    #pragma unroll
    for (int i = 0; i < 2; ++i) {
      int col = (w*2 + i)*16 + m;
      float b0v = ldp(b0s, iblk*128 + col, f32m);
      #pragma unroll
      for (int rr = 0; rr < 4; ++rr)
        ldsH[(qd*4 + rr)*136 + col] = f2b(fmaxf(acc3[i][rr] + b0v, 0.f));
    }
  }
  __syncthreads();

  // ---- stage 4: out = relu(h)@W1 + b1 + net@Wsa + att@Wsb (+ resid) ----
  {
    bf16x8 hf[4];
    #pragma unroll
    for (int ks = 0; ks < 4; ++ks) hf[ks] = *(const bf16x8*)(ldsH + m*136 + ks*32 + qd*8);
    f32x4 acc4[2];
    #pragma unroll
    for (int i = 0; i < 2; ++i) { f32x4 z = {0.f,0.f,0.f,0.f}; acc4[i] = z; }
    #pragma unroll
    for (int i = 0; i < 2; ++i) {
      int cti = w*2 + i;
      const unsigned short* bp1 = W1T + (cti*16 + m)*128 + qd*8;
      #pragma unroll
      for (int ks = 0; ks < 4; ++ks)
        acc4[i] = __builtin_amdgcn_mfma_f32_16x16x32_bf16(hf[ks], *(const bf16x8*)(bp1 + ks*32), acc4[i], 0, 0, 0);
      const unsigned short* bps = WsT + (cti*16 + m)*256 + qd*8;
      #pragma unroll
      for (int ks = 0; ks < 4; ++ks)
        acc4[i] = __builtin_amdgcn_mfma_f32_16x16x32_bf16(nf[ks], *(const bf16x8*)(bps + ks*32), acc4[i], 0, 0, 0);
      #pragma unroll
      for (int ks = 0; ks < 4; ++ks)
        acc4[i] = __builtin_amdgcn_mfma_f32_16x16x32_bf16(af[ks], *(const bf16x8*)(bps + 128 + ks*32), acc4[i], 0, 0, 0);
    }
    #pragma unroll
    for (int i = 0; i < 2; ++i) {
      int col = (w*2 + i)*16 + m;
      float b1v = ldp(b1s, iblk*128 + col, f32m);
      #pragma unroll
      for (int rr = 0; rr < 4; ++rr) {
        int grow2 = r0 + qd*4 + rr;
        float v = acc4[i][rr] + b1v;
        if (hasResid) v += b2f(netIn[grow2*128 + col]);
        netOut[grow2*128 + col] = f2b(v);
      }
    }
  }
}

// ---------------- final: out = net @ W_c + b_c (dtype per flag) ----------------
__global__ __launch_bounds__(256) void k_final(const unsigned short* __restrict__ netIn,
                                               const unsigned short* __restrict__ WcT,
                                               const void* __restrict__ bcv,
                                               const int* __restrict__ flagp,
                                               void* __restrict__ out){
  int tid = threadIdx.x; int w = tid >> 6, lane = tid & 63;
  int f32m = *flagp;
  int r0 = blockIdx.x*16;
  int m = lane & 15, qd = lane >> 4;
  bf16x8 nf[4];
  #pragma unroll
  for (int ks = 0; ks < 4; ++ks)
    nf[ks] = *(const bf16x8*)(netIn + (r0 + m)*128 + ks*32 + qd*8);
  f32x4 acc[2];
  #pragma unroll
  for (int i = 0; i < 2; ++i) { f32x4 z = {0.f,0.f,0.f,0.f}; acc[i] = z; }
  #pragma unroll
  for (int i = 0; i < 2; ++i) {
    int cti = w*2 + i;
    const unsigned short* bp = WcT + (cti*16 + m)*128 + qd*8;
    #pragma unroll
    for (int ks = 0; ks < 4; ++ks)
      acc[i] = __builtin_amdgcn_mfma_f32_16x16x32_bf16(nf[ks], *(const bf16x8*)(bp + ks*32), acc[i], 0, 0, 0);
  }
  if (f32m) {
    float* o = (float*)out;
    #pragma unroll
    for (int i = 0; i < 2; ++i) {
      int col = (w*2 + i)*16 + m;
      float bcf = ldp(bcv, col, 1);
      #pragma unroll
      for (int rr = 0; rr < 4; ++rr)
        o[(r0 + qd*4 + rr)*128 + col] = acc[i][rr] + bcf;
    }
  } else {
    unsigned short* o = (unsigned short*)out;
    #pragma unroll
    for (int i = 0; i < 2; ++i) {
      int col = (w*2 + i)*16 + m;
      float bcf = ldp(bcv, col, 0);
      #pragma unroll
      for (int rr = 0; rr < 4; ++rr)
        o[(r0 + qd*4 + rr)*128 + col] = f2b(acc[i][rr] + bcf);
    }
  }
}

// ---------------- host launch ----------------
extern "C" void kernel_launch(void* const* d_in, const int* in_sizes, int n_in,
                              void* d_out, int out_size, void* d_ws, size_t ws_size,
                              hipStream_t stream){
  const void* p    = d_in[0];
  const void* Wpos = d_in[1];
  const void* bpos = d_in[2];
  const void* W0   = d_in[3];
  const void* b0   = d_in[4];
  const void* W1   = d_in[5];
  const void* b1   = d_in[6];
  const void* Ws   = d_in[7];
  const void* Wc_  = d_in[8];
  const void* bc_  = d_in[9];
  const void* Wo   = d_in[10];
  const void* bo   = d_in[11];
  const void* WC   = d_in[12];
  const void* bC   = d_in[13];

  char* ws = (char*)d_ws;
  int*            flag   = (int*)(ws + 0);                    //      256 B (padded)
  float4*         pf4    = (float4*)(ws + 256);               //   524288 B
  unsigned short* idx16  = (unsigned short*)(ws + 524544);    //  1310720 B
  unsigned short* wsoftb = (unsigned short*)(ws + 1835264);   //  7864320 B
  unsigned short* netA   = (unsigned short*)(ws + 9699584);   //  8388608 B
  unsigned short* wT     = (unsigned short*)(ws + 18088192);  //  1212416 B (total ~19.3 MB)

  k_detect     <<<dim3(1),     dim3(64),  0, stream>>>((const unsigned short*)Wpos, flag);
  k_prep_points<<<dim3(128),   dim3(256), 0, stream>>>(p, flag, pf4);
  k_net0       <<<dim3(16384), dim3(256), 0, stream>>>(pf4, Wpos, bpos, flag, netA);
  k_transpose  <<<dim3(2368),  dim3(256), 0, stream>>>(W0, W1, Ws, Wo, WC, flag, wT);
  k_knn        <<<dim3(512),   dim3(256), 0, stream>>>(pf4, Wc_, bc_, flag, idx16, wsoftb);

  unsigned short* a   = netA;
  unsigned short* bpt = (unsigned short*)d_out;   // d_out as bf16 ping-pong scratch
  for (int i = 0; i < 6; ++i) {
    k_block<<<dim3(2048), dim3(256), 0, stream>>>(a, bpt, idx16, wsoftb, wT,
                                                  b0, b1, bo, flag, i, (i > 0) ? 1 : 0);
    unsigned short* t = a; a = bpt; bpt = t;
  }
  // 6 swaps: final net is in netA (== a)
  k_final<<<dim3(2048), dim3(256), 0, stream>>>(a, wT + 589824, bC, flag, d_out);
}

// Round 8
// 805.505 us; speedup vs baseline: 1.0169x; 1.0169x over previous
//
#include <hip/hip_runtime.h>
#include <hip/hip_bf16.h>
#include <math.h>

#define BB 8
#define TT 4096
#define HHD 128
#define NBK 6
#define KNN 20
#define BT (BB*TT)

typedef __attribute__((ext_vector_type(8))) short bf16x8;
typedef __attribute__((ext_vector_type(4))) float f32x4;

__device__ __forceinline__ float b2f(unsigned short u){
  return __uint_as_float(((unsigned int)u) << 16);
}
__device__ __forceinline__ unsigned short f2b(float f){
  unsigned int x = __float_as_uint(f);
  unsigned int r = (x + 0x7fffu + ((x >> 16) & 1u)) >> 16;   // RTNE
  return (unsigned short)r;
}
// dtype-agnostic parameter load: f32m=1 -> buffer is float32, else bf16
__device__ __forceinline__ float ldp(const void* base, int i, int f32m){
  return f32m ? ((const float*)base)[i] : b2f(((const unsigned short*)base)[i]);
}
__device__ __forceinline__ float lo2f(unsigned int u){ return __uint_as_float(u << 16); }
__device__ __forceinline__ float hi2f(unsigned int u){ return __uint_as_float(u & 0xffff0000u); }
__device__ __forceinline__ unsigned int relu2(unsigned int u){
  unsigned int s = u & 0x80008000u;
  unsigned int m = s | (s - (s >> 15));
  return u & ~m;
}
__device__ __forceinline__ bf16x8 relu8(bf16x8 x){
  union { bf16x8 v; unsigned int u[4]; } t; t.v = x;
  t.u[0] = relu2(t.u[0]); t.u[1] = relu2(t.u[1]);
  t.u[2] = relu2(t.u[2]); t.u[3] = relu2(t.u[3]);
  return t.v;
}

// ---------------- dtype detector ----------------
__global__ void k_detect(const unsigned short* __restrict__ wpos_raw, int* __restrict__ flag){
  if (threadIdx.x == 0 && blockIdx.x == 0) {
    int cnt = 0;
    for (int i = 0; i < 384; ++i) {
      unsigned int e = (wpos_raw[i] >> 7) & 0xFFu;
      if (e >= 0x90u) cnt++;
    }
    *flag = (cnt > 10) ? 1 : 0;
  }
}

// ---------------- prep: p -> float4 (x,y,z,|p|^2) ----------------
__global__ __launch_bounds__(256) void k_prep_points(const void* __restrict__ p,
                                                     const int* __restrict__ flagp,
                                                     float4* __restrict__ pf4){
  int r = blockIdx.x*256 + threadIdx.x;
  if (r >= BT) return;
  int f32m = *flagp;
  float x = ldp(p, r*3+0, f32m), y = ldp(p, r*3+1, f32m), z = ldp(p, r*3+2, f32m);
  float sq = __fadd_rn(__fadd_rn(__fmul_rn(x,x), __fmul_rn(y,y)), __fmul_rn(z,z));
  pf4[r] = make_float4(x, y, z, sq);
}

// ---------------- net0 = p @ W_pos + b_pos  (bf16 out) ----------------
__global__ __launch_bounds__(256) void k_net0(const float4* __restrict__ pf4,
                                              const void* __restrict__ Wpos,
                                              const void* __restrict__ bpos,
                                              const int* __restrict__ flagp,
                                              unsigned short* __restrict__ netA){
  int t = blockIdx.x*256 + threadIdx.x;   // over BT*128
  int f32m = *flagp;
  int c = t & 127, r = t >> 7;
  float4 q = pf4[r];
  float v = ldp(bpos, c, f32m);
  v = fmaf(q.x, ldp(Wpos, c,       f32m), v);
  v = fmaf(q.y, ldp(Wpos, 128 + c, f32m), v);
  v = fmaf(q.z, ldp(Wpos, 256 + c, f32m), v);
  netA[t] = f2b(v);
}

// ---------------- transpose all weights to [N][K] bf16 ----------------
// layout in wT (shorts): W0T 6*32768 | W1T 6*16384 | WsT 6*32768 | WoT 6*16384 | WcT 16384
__global__ __launch_bounds__(256) void k_transpose(const void* __restrict__ W0,
                                                   const void* __restrict__ W1,
                                                   const void* __restrict__ Ws,
                                                   const void* __restrict__ Wo,
                                                   const void* __restrict__ Wc,
                                                   const int* __restrict__ flagp,
                                                   unsigned short* __restrict__ wT){
  int t = blockIdx.x*256 + threadIdx.x;
  int f32m = *flagp;
  if (t < 196608) {                    // W0T: per block [128][256]
    int i = t >> 15; int rem = t & 32767; int n = rem >> 8; int k = rem & 255;
    wT[t] = f2b(ldp(W0, i*32768 + k*128 + n, f32m));
  } else if (t < 294912) {             // W1T: [128][128]
    int u = t - 196608; int i = u >> 14; int rem = u & 16383; int n = rem >> 7; int k = rem & 127;
    wT[t] = f2b(ldp(W1, i*16384 + k*128 + n, f32m));
  } else if (t < 491520) {             // WsT: [128][256]
    int u = t - 294912; int i = u >> 15; int rem = u & 32767; int n = rem >> 8; int k = rem & 255;
    wT[t] = f2b(ldp(Ws, i*32768 + k*128 + n, f32m));
  } else if (t < 589824) {             // WoT: [128][128]
    int u = t - 491520; int i = u >> 14; int rem = u & 16383; int n = rem >> 7; int k = rem & 127;
    wT[t] = f2b(ldp(Wo, i*16384 + k*128 + n, f32m));
  } else if (t < 606208) {             // WcT: [128][128]
    int u = t - 589824; int n = u >> 7; int k = u & 127;
    wT[t] = f2b(ldp(Wc, k*128 + n, f32m));
  }
}

// sorted ascending insert into (ld,li)[20], strict '<' keeps earliest index on ties
#define INS(act, dv, iv) do { bool A_ = (act); float D_ = (dv); int I_ = (iv);        \
  _Pragma("unroll")                                                                    \
  for (int j = 19; j >= 1; --j) {                                                      \
    bool cj = A_ && (D_ < ld[j]); bool cm = A_ && (D_ < ld[j-1]);                      \
    ld[j] = cj ? (cm ? ld[j-1] : D_) : ld[j];                                          \
    li[j] = cj ? (cm ? li[j-1] : I_) : li[j];                                          \
  }                                                                                    \
  { bool c0 = A_ && (D_ < ld[0]); ld[0] = c0 ? D_ : ld[0]; li[0] = c0 ? I_ : li[0]; } \
} while(0)

// ---------------- KNN: 8-way partition, 32 queries/block ----------------
// Block = 4 waves; query = lane&31, partition = w*2 + (lane>>5) (512 cands each).
// 1024 blocks -> 4 waves/SIMD (2x round-6 parallelism, half per-wave work).
// Tile is wave-private (no scan barriers). 8-way ascending-partition merge with
// strict '<' preserves stable top_k tie semantics.
__global__ __launch_bounds__(256) void k_knn(const float4* __restrict__ pf4,
                                             const void* __restrict__ Wc,
                                             const void* __restrict__ bc,
                                             const int* __restrict__ flagp,
                                             unsigned short* __restrict__ idx16,
                                             unsigned short* __restrict__ wsoftb){
  __shared__ char smem[40960];
  float4* tile = (float4*)smem;                 // scan: [4 waves][512] float4 = 32 KB
  float*  lsd  = (float*)smem;                  // merge: [256][20] = 20 KB
  int*    lsi  = (int*)(smem + 20480);          // merge: [256][20] = 20 KB

  int tid  = threadIdx.x;
  int w    = tid >> 6, lane = tid & 63;
  int half = lane >> 5;
  int qi   = lane & 31;
  int part = (w << 1) | half;                   // 0..7
  int rq   = blockIdx.x*32 + qi;                // 1024 blocks x 32 queries
  int b    = rq >> 12;
  int f32m = *flagp;
  float4 q = pf4[rq];

  float ld[20]; int li[20];
  #pragma unroll
  for (int j = 0; j < 20; ++j) { ld[j] = 3.0e38f; li[j] = 0; }
  float thresh = 3.0e38f;
  float bd0=0.f,bd1=0.f,bd2=0.f,bd3=0.f; int bi0=0,bi1=0,bi2=0,bi3=0; int cnt=0;

  for (int ch = 0; ch < 2; ++ch) {
    // wave-private tile quarter: load chunk ch of partitions 2w and 2w+1
    {
      const float4* base0 = pf4 + (b << 12) + (w*2    )*512 + ch*256;
      const float4* base1 = pf4 + (b << 12) + (w*2 + 1)*512 + ch*256;
      float4* tw = tile + w*512;
      #pragma unroll
      for (int i = 0; i < 4; ++i) tw[lane + i*64]       = base0[lane + i*64];
      #pragma unroll
      for (int i = 0; i < 4; ++i) tw[256 + lane + i*64] = base1[lane + i*64];
    }
    // same wave reads what it just wrote: sequential wave execution, no barrier
    int baseI = part*512 + ch*256;
    const float4* tp = tile + w*512 + half*256;
    for (int j = 0; j < 256; ++j) {
      float4 pt = tp[j];
      float dot = __fadd_rn(__fadd_rn(__fmul_rn(q.x,pt.x), __fmul_rn(q.y,pt.y)),
                            __fmul_rn(q.z,pt.z));
      float d2  = __fsub_rn(__fadd_rn(q.w, pt.w), __fmul_rn(2.0f, dot));
      bool take = d2 < thresh;       // upper bound of true 20th-best: never drops a keeper
      int  gi   = baseI + j;
      bool t0 = take && (cnt == 0); bd0 = t0 ? d2 : bd0; bi0 = t0 ? gi : bi0;
      bool t1 = take && (cnt == 1); bd1 = t1 ? d2 : bd1; bi1 = t1 ? gi : bi1;
      bool t2 = take && (cnt == 2); bd2 = t2 ? d2 : bd2; bi2 = t2 ? gi : bi2;
      bool t3 = take && (cnt == 3); bd3 = t3 ? d2 : bd3; bi3 = t3 ? gi : bi3;
      cnt += take ? 1 : 0;
      if (__ballot(cnt >= 4)) {      // wave-uniform branch
        INS(cnt > 0, bd0, bi0); INS(cnt > 1, bd1, bi1);
        INS(cnt > 2, bd2, bi2); INS(cnt > 3, bd3, bi3);
        cnt = 0; thresh = ld[19];
      }
    }
  }
  INS(cnt > 0, bd0, bi0); INS(cnt > 1, bd1, bi1);
  INS(cnt > 2, bd2, bi2); INS(cnt > 3, bd3, bi3);

  __syncthreads();                   // scan done; tile region reused as lsd/lsi
  #pragma unroll
  for (int j = 0; j < 20; ++j) { lsd[tid*20 + j] = ld[j]; lsi[tid*20 + j] = li[j]; }
  __syncthreads();

  if (tid < 32) {                    // merger thread per query: 8-way merge
    // thread index of partition p's list for query tid: (p>>1)*64 + (p&1)*32 + tid
    int hp[8];
    #pragma unroll
    for (int pp = 0; pp < 8; ++pp) hp[pp] = ((pp >> 1)*64 + (pp & 1)*32 + tid)*20;
    int ip[8];
    #pragma unroll
    for (int pp = 0; pp < 8; ++pp) ip[pp] = 0;
    float dis[20]; int outi[20];
    for (int o = 0; o < 20; ++o) {
      float bd = lsd[hp[0] + ip[0]]; int sel = 0;
      #pragma unroll
      for (int pp = 1; pp < 8; ++pp) {
        float dv = lsd[hp[pp] + ip[pp]];
        if (dv < bd) { bd = dv; sel = pp; }   // strict <: lowest partition wins ties
      }
      outi[o] = lsi[hp[sel] + ip[sel]];
      ip[sel]++;
      dis[o] = sqrtf(fmaxf(bd, 1e-12f));
    }
    // ---- fused attention softmax weights, all 6 blocks ----
    float nx[20], ny[20], nz[20];
    #pragma unroll 4
    for (int k = 0; k < 20; ++k) {
      idx16[rq*20 + k] = (unsigned short)outi[k];
      float4 pp = pf4[(b << 12) + outi[k]];
      nx[k] = pp.x; ny[k] = pp.y; nz[k] = pp.z;
    }
    for (int i = 0; i < NBK; ++i) {
      float w0 = ldp(Wc,i*7+0,f32m), w1 = ldp(Wc,i*7+1,f32m), w2 = ldp(Wc,i*7+2,f32m);
      float w3 = ldp(Wc,i*7+3,f32m), w4 = ldp(Wc,i*7+4,f32m), w5 = ldp(Wc,i*7+5,f32m);
      float w6 = ldp(Wc,i*7+6,f32m);
      float bci = ldp(bc,i,f32m);
      float s[20]; float mx = -3.0e38f;
      #pragma unroll
      for (int k = 0; k < 20; ++k) {
        float v = bci;
        v = fmaf(dis[k], w0, v);
        v = fmaf(nx[k], w1, v); v = fmaf(ny[k], w2, v); v = fmaf(nz[k], w3, v);
        v = fmaf(q.x, w4, v);  v = fmaf(q.y, w5, v);  v = fmaf(q.z, w6, v);
        s[k] = v; mx = fmaxf(mx, v);
      }
      float sum = 0.f;
      #pragma unroll
      for (int k = 0; k < 20; ++k) { float e = __expf(s[k] - mx); s[k] = e; sum += e; }
      float inv = 1.0f / sum;
      #pragma unroll
      for (int k = 0; k < 20; ++k) wsoftb[(rq*6 + i)*20 + k] = f2b(s[k]*inv);
    }
  }
}

// ---------------- one resnet block (fused gather+attention+GEMMs) ----------------
// round-6 proven config: 1024 blocks x 32 rows; two 16-row tiles per block, each
// tile served by 2 waves (each owns 64 of 128 output cols).
__global__ __launch_bounds__(256) void k_block(const unsigned short* __restrict__ netIn,
                                               unsigned short* __restrict__ netOut,
                                               const unsigned short* __restrict__ idx16,
                                               const unsigned short* __restrict__ wsoftb,
                                               const unsigned short* __restrict__ wT,
                                               const void* __restrict__ b0s,
                                               const void* __restrict__ b1s,
                                               const void* __restrict__ bos,
                                               const int* __restrict__ flagp,
                                               int iblk, int hasResid){
  __shared__ unsigned short ldsA[2][16*136];
  __shared__ unsigned short ldsH[2][16*136];
  int tid = threadIdx.x;
  int f32m = *flagp;
  int w = tid >> 6, lane = tid & 63;
  int t = w >> 1;            // row tile 0/1
  int c = w & 1;             // col half 0/1
  int b  = blockIdx.x & 7;   // XCD swizzle: gathers stay within one batch's net
  int r0 = (b << 12) + ((blockIdx.x >> 3) << 5) + (t << 4);
  const unsigned short* W0T = wT + iblk*32768;
  const unsigned short* W1T = wT + 196608 + iblk*16384;
  const unsigned short* WsT = wT + 294912 + iblk*32768;
  const unsigned short* WoT = wT + 491520 + iblk*16384;
  int m = lane & 15, qd = lane >> 4;

  // ---- stage 1: attsum[r][cols c*64+cg*16 .. +16] = sum_k w * netIn[idx_k] ----
  {
    int r = lane >> 2, cg = lane & 3;
    int grow = r0 + r;
    int cbase = c*64 + cg*16;
    float acc[16];
    #pragma unroll
    for (int j = 0; j < 16; ++j) acc[j] = 0.f;
    #pragma unroll 4
    for (int k = 0; k < 20; ++k) {
      int nb = idx16[grow*20 + k] & 4095;
      float wk = b2f(wsoftb[(grow*6 + iblk)*20 + k]);
      const uint4* np_ = (const uint4*)(netIn + ((b << 12) + nb)*128 + cbase);
      #pragma unroll
      for (int u = 0; u < 2; ++u) {
        uint4 uu = np_[u];
        acc[u*8+0] = fmaf(wk, lo2f(uu.x), acc[u*8+0]);
        acc[u*8+1] = fmaf(wk, hi2f(uu.x), acc[u*8+1]);
        acc[u*8+2] = fmaf(wk, lo2f(uu.y), acc[u*8+2]);
        acc[u*8+3] = fmaf(wk, hi2f(uu.y), acc[u*8+3]);
        acc[u*8+4] = fmaf(wk, lo2f(uu.z), acc[u*8+4]);
        acc[u*8+5] = fmaf(wk, hi2f(uu.z), acc[u*8+5]);
        acc[u*8+6] = fmaf(wk, lo2f(uu.w), acc[u*8+6]);
        acc[u*8+7] = fmaf(wk, hi2f(uu.w), acc[u*8+7]);
      }
    }
    unsigned short* hb = ldsH[t];
    #pragma unroll
    for (int j = 0; j < 8; ++j) {
      unsigned int pr = ((unsigned int)f2b(acc[2*j+1]) << 16) | (unsigned int)f2b(acc[2*j]);
      *(unsigned int*)(hb + r*136 + cbase + 2*j) = pr;
    }
  }
  __syncthreads();

  // ---- stage 2: att = attsum @ Wo^T + bo -> ldsA (4 col-tiles per wave) ----
  {
    bf16x8 asf[4];
    #pragma unroll
    for (int ks = 0; ks < 4; ++ks)
      asf[ks] = *(const bf16x8*)(ldsH[t] + m*136 + ks*32 + qd*8);
    f32x4 acc2[4];
    #pragma unroll
    for (int i = 0; i < 4; ++i) { f32x4 z = {0.f,0.f,0.f,0.f}; acc2[i] = z; }
    #pragma unroll
    for (int i = 0; i < 4; ++i) {
      int cti = c*4 + i;
      const unsigned short* bp = WoT + (cti*16 + m)*128 + qd*8;
      #pragma unroll
      for (int ks = 0; ks < 4; ++ks)
        acc2[i] = __builtin_amdgcn_mfma_f32_16x16x32_bf16(asf[ks], *(const bf16x8*)(bp + ks*32), acc2[i], 0, 0, 0);
    }
    unsigned short* ab = ldsA[t];
    #pragma unroll
    for (int i = 0; i < 4; ++i) {
      int col = (c*4 + i)*16 + m;
      float bo = ldp(bos, iblk*128 + col, f32m);
      #pragma unroll
      for (int rr = 0; rr < 4; ++rr)
        ab[(qd*4 + rr)*136 + col] = f2b(acc2[i][rr] + bo);
    }
  }
  __syncthreads();

  // ---- stage 3: h = relu(net)@W0a + relu(att)@W0b + b0; relu(h) -> ldsH ----
  bf16x8 nf[4], af[4];
  {
    const unsigned short* nrow = netIn + (r0 + m)*128;
    #pragma unroll
    for (int ks = 0; ks < 4; ++ks) nf[ks] = *(const bf16x8*)(nrow + ks*32 + qd*8);
    #pragma unroll
    for (int ks = 0; ks < 4; ++ks) af[ks] = *(const bf16x8*)(ldsA[t] + m*136 + ks*32 + qd*8);
    bf16x8 rnf[4], raf[4];
    #pragma unroll
    for (int ks = 0; ks < 4; ++ks) { rnf[ks] = relu8(nf[ks]); raf[ks] = relu8(af[ks]); }
    f32x4 acc3[4];
    #pragma unroll
    for (int i = 0; i < 4; ++i) { f32x4 z = {0.f,0.f,0.f,0.f}; acc3[i] = z; }
    #pragma unroll
    for (int i = 0; i < 4; ++i) {
      int cti = c*4 + i;
      const unsigned short* bp = W0T + (cti*16 + m)*256 + qd*8;
      #pragma unroll
      for (int ks = 0; ks < 4; ++ks)
        acc3[i] = __builtin_amdgcn_mfma_f32_16x16x32_bf16(rnf[ks], *(const bf16x8*)(bp + ks*32), acc3[i], 0, 0, 0);
      #pragma unroll
      for (int ks = 0; ks < 4; ++ks)
        acc3[i] = __builtin_amdgcn_mfma_f32_16x16x32_bf16(raf[ks], *(const bf16x8*)(bp + 128 + ks*32), acc3[i], 0, 0, 0);
    }
    unsigned short* hb = ldsH[t];
    #pragma unroll
    for (int i = 0; i < 4; ++i) {
      int col = (c*4 + i)*16 + m;
      float b0v = ldp(b0s, iblk*128 + col, f32m);
      #pragma unroll
      for (int rr = 0; rr < 4; ++rr)
        hb[(qd*4 + rr)*136 + col] = f2b(fmaxf(acc3[i][rr] + b0v, 0.f));
    }
  }
  __syncthreads();

  // ---- stage 4: out = relu(h)@W1 + b1 + net@Wsa + att@Wsb (+ resid) ----
  {
    bf16x8 hf[4];
    #pragma unroll
    for (int ks = 0; ks < 4; ++ks) hf[ks] = *(const bf16x8*)(ldsH[t] + m*136 + ks*32 + qd*8);
    f32x4 acc4[4];
    #pragma unroll
    for (int i = 0; i < 4; ++i) { f32x4 z = {0.f,0.f,0.f,0.f}; acc4[i] = z; }
    #pragma unroll
    for (int i = 0; i < 4; ++i) {
      int cti = c*4 + i;
      const unsigned short* bp1 = W1T + (cti*16 + m)*128 + qd*8;
      #pragma unroll
      for (int ks = 0; ks < 4; ++ks)
        acc4[i] = __builtin_amdgcn_mfma_f32_16x16x32_bf16(hf[ks], *(const bf16x8*)(bp1 + ks*32), acc4[i], 0, 0, 0);
      const unsigned short* bps = WsT + (cti*16 + m)*256 + qd*8;
      #pragma unroll
      for (int ks = 0; ks < 4; ++ks)
        acc4[i] = __builtin_amdgcn_mfma_f32_16x16x32_bf16(nf[ks], *(const bf16x8*)(bps + ks*32), acc4[i], 0, 0, 0);
      #pragma unroll
      for (int ks = 0; ks < 4; ++ks)
        acc4[i] = __builtin_amdgcn_mfma_f32_16x16x32_bf16(af[ks], *(const bf16x8*)(bps + 128 + ks*32), acc4[i], 0, 0, 0);
    }
    #pragma unroll
    for (int i = 0; i < 4; ++i) {
      int col = (c*4 + i)*16 + m;
      float b1v = ldp(b1s, iblk*128 + col, f32m);
      #pragma unroll
      for (int rr = 0; rr < 4; ++rr) {
        int grow2 = r0 + qd*4 + rr;
        float v = acc4[i][rr] + b1v;
        if (hasResid) v += b2f(netIn[grow2*128 + col]);
        netOut[grow2*128 + col] = f2b(v);
      }
    }
  }
}

// ---------------- final: out = net @ W_c + b_c (dtype per flag) ----------------
__global__ __launch_bounds__(256) void k_final(const unsigned short* __restrict__ netIn,
                                               const unsigned short* __restrict__ WcT,
                                               const void* __restrict__ bcv,
                                               const int* __restrict__ flagp,
                                               void* __restrict__ out){
  int tid = threadIdx.x; int w = tid >> 6, lane = tid & 63;
  int f32m = *flagp;
  int t = w >> 1, c = w & 1;
  int r0 = blockIdx.x*32 + t*16;
  int m = lane & 15, qd = lane >> 4;
  bf16x8 nf[4];
  #pragma unroll
  for (int ks = 0; ks < 4; ++ks)
    nf[ks] = *(const bf16x8*)(netIn + (r0 + m)*128 + ks*32 + qd*8);
  f32x4 acc[4];
  #pragma unroll
  for (int i = 0; i < 4; ++i) { f32x4 z = {0.f,0.f,0.f,0.f}; acc[i] = z; }
  #pragma unroll
  for (int i = 0; i < 4; ++i) {
    int cti = c*4 + i;
    const unsigned short* bp = WcT + (cti*16 + m)*128 + qd*8;
    #pragma unroll
    for (int ks = 0; ks < 4; ++ks)
      acc[i] = __builtin_amdgcn_mfma_f32_16x16x32_bf16(nf[ks], *(const bf16x8*)(bp + ks*32), acc[i], 0, 0, 0);
  }
  if (f32m) {
    float* o = (float*)out;
    #pragma unroll
    for (int i = 0; i < 4; ++i) {
      int col = (c*4 + i)*16 + m;
      float bcf = ldp(bcv, col, 1);
      #pragma unroll
      for (int rr = 0; rr < 4; ++rr)
        o[(r0 + qd*4 + rr)*128 + col] = acc[i][rr] + bcf;
    }
  } else {
    unsigned short* o = (unsigned short*)out;
    #pragma unroll
    for (int i = 0; i < 4; ++i) {
      int col = (c*4 + i)*16 + m;
      float bcf = ldp(bcv, col, 0);
      #pragma unroll
      for (int rr = 0; rr < 4; ++rr)
        o[(r0 + qd*4 + rr)*128 + col] = f2b(acc[i][rr] + bcf);
    }
  }
}

// ---------------- host launch ----------------
extern "C" void kernel_launch(void* const* d_in, const int* in_sizes, int n_in,
                              void* d_out, int out_size, void* d_ws, size_t ws_size,
                              hipStream_t stream){
  const void* p    = d_in[0];
  const void* Wpos = d_in[1];
  const void* bpos = d_in[2];
  const void* W0   = d_in[3];
  const void* b0   = d_in[4];
  const void* W1   = d_in[5];
  const void* b1   = d_in[6];
  const void* Ws   = d_in[7];
  const void* Wc_  = d_in[8];
  const void* bc_  = d_in[9];
  const void* Wo   = d_in[10];
  const void* bo   = d_in[11];
  const void* WC   = d_in[12];
  const void* bC   = d_in[13];

  char* ws = (char*)d_ws;
  int*            flag   = (int*)(ws + 0);                    //      256 B (padded)
  float4*         pf4    = (float4*)(ws + 256);               //   524288 B
  unsigned short* idx16  = (unsigned short*)(ws + 524544);    //  1310720 B
  unsigned short* wsoftb = (unsigned short*)(ws + 1835264);   //  7864320 B
  unsigned short* netA   = (unsigned short*)(ws + 9699584);   //  8388608 B
  unsigned short* wT     = (unsigned short*)(ws + 18088192);  //  1212416 B (total ~19.3 MB)

  k_detect     <<<dim3(1),     dim3(64),  0, stream>>>((const unsigned short*)Wpos, flag);
  k_prep_points<<<dim3(128),   dim3(256), 0, stream>>>(p, flag, pf4);
  k_net0       <<<dim3(16384), dim3(256), 0, stream>>>(pf4, Wpos, bpos, flag, netA);
  k_transpose  <<<dim3(2368),  dim3(256), 0, stream>>>(W0, W1, Ws, Wo, WC, flag, wT);
  k_knn        <<<dim3(1024),  dim3(256), 0, stream>>>(pf4, Wc_, bc_, flag, idx16, wsoftb);

  unsigned short* a   = netA;
  unsigned short* bpt = (unsigned short*)d_out;   // d_out as bf16 ping-pong scratch
  for (int i = 0; i < 6; ++i) {
    k_block<<<dim3(1024), dim3(256), 0, stream>>>(a, bpt, idx16, wsoftb, wT,
                                                  b0, b1, bo, flag, i, (i > 0) ? 1 : 0);
    unsigned short* t = a; a = bpt; bpt = t;
  }
  // 6 swaps: final net is in netA (== a)
  k_final<<<dim3(1024), dim3(256), 0, stream>>>(a, wT + 589824, bC, flag, d_out);
}

// Round 9
// 746.798 us; speedup vs baseline: 1.0968x; 1.0786x over previous
//
#include <hip/hip_runtime.h>
#include <hip/hip_bf16.h>
#include <math.h>

#define BB 8
#define TT 4096
#define HHD 128
#define NBK 6
#define KNN 20
#define BT (BB*TT)

typedef __attribute__((ext_vector_type(8))) short bf16x8;
typedef __attribute__((ext_vector_type(4))) float f32x4;

__device__ __forceinline__ float b2f(unsigned short u){
  return __uint_as_float(((unsigned int)u) << 16);
}
__device__ __forceinline__ unsigned short f2b(float f){
  unsigned int x = __float_as_uint(f);
  unsigned int r = (x + 0x7fffu + ((x >> 16) & 1u)) >> 16;   // RTNE
  return (unsigned short)r;
}
// dtype-agnostic parameter load: f32m=1 -> buffer is float32, else bf16
__device__ __forceinline__ float ldp(const void* base, int i, int f32m){
  return f32m ? ((const float*)base)[i] : b2f(((const unsigned short*)base)[i]);
}
__device__ __forceinline__ float lo2f(unsigned int u){ return __uint_as_float(u << 16); }
__device__ __forceinline__ float hi2f(unsigned int u){ return __uint_as_float(u & 0xffff0000u); }
__device__ __forceinline__ unsigned int relu2(unsigned int u){
  unsigned int s = u & 0x80008000u;
  unsigned int m = s | (s - (s >> 15));
  return u & ~m;
}
__device__ __forceinline__ bf16x8 relu8(bf16x8 x){
  union { bf16x8 v; unsigned int u[4]; } t; t.v = x;
  t.u[0] = relu2(t.u[0]); t.u[1] = relu2(t.u[1]);
  t.u[2] = relu2(t.u[2]); t.u[3] = relu2(t.u[3]);
  return t.v;
}

// ---------------- dtype detector ----------------
__global__ void k_detect(const unsigned short* __restrict__ wpos_raw, int* __restrict__ flag){
  if (threadIdx.x == 0 && blockIdx.x == 0) {
    int cnt = 0;
    for (int i = 0; i < 384; ++i) {
      unsigned int e = (wpos_raw[i] >> 7) & 0xFFu;
      if (e >= 0x90u) cnt++;
    }
    *flag = (cnt > 10) ? 1 : 0;
  }
}

// ---------------- prep: p -> float4 (x,y,z,|p|^2) ----------------
__global__ __launch_bounds__(256) void k_prep_points(const void* __restrict__ p,
                                                     const int* __restrict__ flagp,
                                                     float4* __restrict__ pf4){
  int r = blockIdx.x*256 + threadIdx.x;
  if (r >= BT) return;
  int f32m = *flagp;
  float x = ldp(p, r*3+0, f32m), y = ldp(p, r*3+1, f32m), z = ldp(p, r*3+2, f32m);
  float sq = __fadd_rn(__fadd_rn(__fmul_rn(x,x), __fmul_rn(y,y)), __fmul_rn(z,z));
  pf4[r] = make_float4(x, y, z, sq);
}

// ---------------- net0 = p @ W_pos + b_pos  (bf16 out) ----------------
__global__ __launch_bounds__(256) void k_net0(const float4* __restrict__ pf4,
                                              const void* __restrict__ Wpos,
                                              const void* __restrict__ bpos,
                                              const int* __restrict__ flagp,
                                              unsigned short* __restrict__ netA){
  int t = blockIdx.x*256 + threadIdx.x;   // over BT*128
  int f32m = *flagp;
  int c = t & 127, r = t >> 7;
  float4 q = pf4[r];
  float v = ldp(bpos, c, f32m);
  v = fmaf(q.x, ldp(Wpos, c,       f32m), v);
  v = fmaf(q.y, ldp(Wpos, 128 + c, f32m), v);
  v = fmaf(q.z, ldp(Wpos, 256 + c, f32m), v);
  netA[t] = f2b(v);
}

// ---------------- transpose all weights to [N][K] bf16 ----------------
// layout in wT (shorts): W0T 6*32768 | W1T 6*16384 | WsT 6*32768 | WoT 6*16384 | WcT 16384
__global__ __launch_bounds__(256) void k_transpose(const void* __restrict__ W0,
                                                   const void* __restrict__ W1,
                                                   const void* __restrict__ Ws,
                                                   const void* __restrict__ Wo,
                                                   const void* __restrict__ Wc,
                                                   const int* __restrict__ flagp,
                                                   unsigned short* __restrict__ wT){
  int t = blockIdx.x*256 + threadIdx.x;
  int f32m = *flagp;
  if (t < 196608) {                    // W0T: per block [128][256]
    int i = t >> 15; int rem = t & 32767; int n = rem >> 8; int k = rem & 255;
    wT[t] = f2b(ldp(W0, i*32768 + k*128 + n, f32m));
  } else if (t < 294912) {             // W1T: [128][128]
    int u = t - 196608; int i = u >> 14; int rem = u & 16383; int n = rem >> 7; int k = rem & 127;
    wT[t] = f2b(ldp(W1, i*16384 + k*128 + n, f32m));
  } else if (t < 491520) {             // WsT: [128][256]
    int u = t - 294912; int i = u >> 15; int rem = u & 32767; int n = rem >> 8; int k = rem & 255;
    wT[t] = f2b(ldp(Ws, i*32768 + k*128 + n, f32m));
  } else if (t < 589824) {             // WoT: [128][128]
    int u = t - 491520; int i = u >> 14; int rem = u & 16383; int n = rem >> 7; int k = rem & 127;
    wT[t] = f2b(ldp(Wo, i*16384 + k*128 + n, f32m));
  } else if (t < 606208) {             // WcT: [128][128]
    int u = t - 589824; int n = u >> 7; int k = u & 127;
    wT[t] = f2b(ldp(Wc, k*128 + n, f32m));
  }
}

// sorted ascending insert into (ld,li)[20], strict '<' keeps earliest index on ties
#define INS(act, dv, iv) do { bool A_ = (act); float D_ = (dv); int I_ = (iv);        \
  _Pragma("unroll")                                                                    \
  for (int j = 19; j >= 1; --j) {                                                      \
    bool cj = A_ && (D_ < ld[j]); bool cm = A_ && (D_ < ld[j-1]);                      \
    ld[j] = cj ? (cm ? ld[j-1] : D_) : ld[j];                                          \
    li[j] = cj ? (cm ? li[j-1] : I_) : li[j];                                          \
  }                                                                                    \
  { bool c0 = A_ && (D_ < ld[0]); ld[0] = c0 ? D_ : ld[0]; li[0] = c0 ? I_ : li[0]; } \
} while(0)

// ---------------- KNN: 4 waves/query-group, partitioned candidates ----------------
// (round-4/6 proven version, restored verbatim — 4 partitions is the select-work
// sweet spot; 8 partitions raised total insert work 1.7x and regressed)
__global__ __launch_bounds__(256) void k_knn(const float4* __restrict__ pf4,
                                             const void* __restrict__ Wc,
                                             const void* __restrict__ bc,
                                             const int* __restrict__ flagp,
                                             unsigned short* __restrict__ idx16,
                                             unsigned short* __restrict__ wsoftb){
  __shared__ char smem[40960];
  float4* tile = (float4*)smem;                 // [4][256] float4 = 16 KB (scan phase)
  float*  lsd  = (float*)smem;                  // [256][20] = 20 KB (merge phase)
  int*    lsi  = (int*)(smem + 20480);          // [256][20] = 20 KB

  int tid  = threadIdx.x;
  int part = tid >> 6, lane = tid & 63;
  int rq   = blockIdx.x*64 + lane;              // query row (512 blocks x 64)
  int b    = rq >> 12;
  int f32m = *flagp;
  float4 q = pf4[rq];

  float ld[20]; int li[20];
  #pragma unroll
  for (int j = 0; j < 20; ++j) { ld[j] = 3.0e38f; li[j] = 0; }
  float thresh = 3.0e38f;
  float bd0=0.f,bd1=0.f,bd2=0.f,bd3=0.f; int bi0=0,bi1=0,bi2=0,bi3=0; int cnt=0;

  for (int ch = 0; ch < 4; ++ch) {
    __syncthreads();
    {
      const float4* src = pf4 + (b << 12) + part*1024 + ch*256;
      tile[part*256 + lane      ] = src[lane      ];
      tile[part*256 + lane +  64] = src[lane +  64];
      tile[part*256 + lane + 128] = src[lane + 128];
      tile[part*256 + lane + 192] = src[lane + 192];
    }
    __syncthreads();
    int baseI = part*1024 + ch*256;
    for (int j = 0; j < 256; ++j) {
      float4 pt = tile[part*256 + j];
      float dot = __fadd_rn(__fadd_rn(__fmul_rn(q.x,pt.x), __fmul_rn(q.y,pt.y)),
                            __fmul_rn(q.z,pt.z));
      float d2  = __fsub_rn(__fadd_rn(q.w, pt.w), __fmul_rn(2.0f, dot));
      bool take = d2 < thresh;       // thresh is upper bound of true 20th-best: never drops a keeper
      int  gi   = baseI + j;
      bool t0 = take && (cnt == 0); bd0 = t0 ? d2 : bd0; bi0 = t0 ? gi : bi0;
      bool t1 = take && (cnt == 1); bd1 = t1 ? d2 : bd1; bi1 = t1 ? gi : bi1;
      bool t2 = take && (cnt == 2); bd2 = t2 ? d2 : bd2; bi2 = t2 ? gi : bi2;
      bool t3 = take && (cnt == 3); bd3 = t3 ? d2 : bd3; bi3 = t3 ? gi : bi3;
      cnt += take ? 1 : 0;
      if (__ballot(cnt >= 4)) {      // wave-uniform branch
        INS(cnt > 0, bd0, bi0); INS(cnt > 1, bd1, bi1);
        INS(cnt > 2, bd2, bi2); INS(cnt > 3, bd3, bi3);
        cnt = 0; thresh = ld[19];
      }
    }
  }
  INS(cnt > 0, bd0, bi0); INS(cnt > 1, bd1, bi1);
  INS(cnt > 2, bd2, bi2); INS(cnt > 3, bd3, bi3);

  __syncthreads();                   // scan done; tile region reused as lsd/lsi
  #pragma unroll
  for (int j = 0; j < 20; ++j) { lsd[tid*20 + j] = ld[j]; lsi[tid*20 + j] = li[j]; }
  __syncthreads();

  if (tid < 64) {                    // lane q of wave 0 merges query q's 4 lists
    int p0 = tid*20, p1 = (64+tid)*20, p2 = (128+tid)*20, p3 = (192+tid)*20;
    int i0=0, i1=0, i2=0, i3=0;
    float dis[20]; int outi[20];
    #pragma unroll 4
    for (int o = 0; o < 20; ++o) {
      float d0 = lsd[p0+i0], d1 = lsd[p1+i1], d2v = lsd[p2+i2], d3 = lsd[p3+i3];
      float bd = d0; int sel = 0;
      if (d1  < bd) { bd = d1;  sel = 1; }    // strict <: lowest partition wins ties
      if (d2v < bd) { bd = d2v; sel = 2; }
      if (d3  < bd) { bd = d3;  sel = 3; }
      int bi = (sel==0) ? lsi[p0+i0] : (sel==1) ? lsi[p1+i1] : (sel==2) ? lsi[p2+i2] : lsi[p3+i3];
      i0 += (sel==0); i1 += (sel==1); i2 += (sel==2); i3 += (sel==3);
      dis[o] = sqrtf(fmaxf(bd, 1e-12f));
      outi[o] = bi;
    }
    // ---- fused attention softmax weights, all 6 blocks ----
    float nx[20], ny[20], nz[20];
    #pragma unroll 4
    for (int k = 0; k < 20; ++k) {
      idx16[rq*20 + k] = (unsigned short)outi[k];
      float4 pp = pf4[(b << 12) + outi[k]];
      nx[k] = pp.x; ny[k] = pp.y; nz[k] = pp.z;
    }
    for (int i = 0; i < NBK; ++i) {
      float w0 = ldp(Wc,i*7+0,f32m), w1 = ldp(Wc,i*7+1,f32m), w2 = ldp(Wc,i*7+2,f32m);
      float w3 = ldp(Wc,i*7+3,f32m), w4 = ldp(Wc,i*7+4,f32m), w5 = ldp(Wc,i*7+5,f32m);
      float w6 = ldp(Wc,i*7+6,f32m);
      float bci = ldp(bc,i,f32m);
      float s[20]; float mx = -3.0e38f;
      #pragma unroll
      for (int k = 0; k < 20; ++k) {
        float v = bci;
        v = fmaf(dis[k], w0, v);
        v = fmaf(nx[k], w1, v); v = fmaf(ny[k], w2, v); v = fmaf(nz[k], w3, v);
        v = fmaf(q.x, w4, v);  v = fmaf(q.y, w5, v);  v = fmaf(q.z, w6, v);
        s[k] = v; mx = fmaxf(mx, v);
      }
      float sum = 0.f;
      #pragma unroll
      for (int k = 0; k < 20; ++k) { float e = __expf(s[k] - mx); s[k] = e; sum += e; }
      float inv = 1.0f / sum;
      #pragma unroll
      for (int k = 0; k < 20; ++k) wsoftb[(rq*6 + i)*20 + k] = f2b(s[k]*inv);
    }
  }
}

// ---------------- one resnet block (fused gather+attention+GEMMs) ----------------
// R6 structure (1024 blocks x 32 rows, col-split) + MLP fix: all B-fragments of
// each stage preloaded into registers before the MFMA chain (the old code issued
// ~96 dependent L2 loads interleaved with MFMAs -> latency-serialized at 88 VGPR).
// __launch_bounds__(256,1) unlocks the VGPR budget (~290 peak, no spill at <512).
__global__ __launch_bounds__(256, 1) void k_block(const unsigned short* __restrict__ netIn,
                                                  unsigned short* __restrict__ netOut,
                                                  const unsigned short* __restrict__ idx16,
                                                  const unsigned short* __restrict__ wsoftb,
                                                  const unsigned short* __restrict__ wT,
                                                  const void* __restrict__ b0s,
                                                  const void* __restrict__ b1s,
                                                  const void* __restrict__ bos,
                                                  const int* __restrict__ flagp,
                                                  int iblk, int hasResid){
  __shared__ unsigned short ldsA[2][16*136];
  __shared__ unsigned short ldsH[2][16*136];
  int tid = threadIdx.x;
  int f32m = *flagp;
  int w = tid >> 6, lane = tid & 63;
  int t = w >> 1;            // row tile 0/1
  int c = w & 1;             // col half 0/1
  int b  = blockIdx.x & 7;   // XCD swizzle: gathers stay within one batch's net
  int r0 = (b << 12) + ((blockIdx.x >> 3) << 5) + (t << 4);
  const unsigned short* W0T = wT + iblk*32768;
  const unsigned short* W1T = wT + 196608 + iblk*16384;
  const unsigned short* WsT = wT + 294912 + iblk*32768;
  const unsigned short* WoT = wT + 491520 + iblk*16384;
  int m = lane & 15, qd = lane >> 4;

  // ---- stage 1: attsum[r][cbase..cbase+16] = sum_k w * netIn[idx_k] ----
  // two-phase: batch-load idx+weights, then neighbor rows in bursts of 10.
  {
    int r = lane >> 2, cg = lane & 3;
    int grow = r0 + r;
    int cbase = c*64 + cg*16;
    const unsigned int* ip = (const unsigned int*)(idx16 + grow*20);
    const unsigned int* wp = (const unsigned int*)(wsoftb + (grow*6 + iblk)*20);
    unsigned int iv[10], wv[10];
    #pragma unroll
    for (int j = 0; j < 10; ++j) iv[j] = ip[j];
    #pragma unroll
    for (int j = 0; j < 10; ++j) wv[j] = wp[j];
    float acc[16];
    #pragma unroll
    for (int j = 0; j < 16; ++j) acc[j] = 0.f;
    #pragma unroll
    for (int h = 0; h < 2; ++h) {
      uint4 gb[10][2];
      #pragma unroll
      for (int j = 0; j < 5; ++j) {
        unsigned int pair = iv[h*5 + j];
        int nb0 = (int)(pair & 0xFFFFu) & 4095;
        int nb1 = (int)(pair >> 16) & 4095;
        const uint4* p0 = (const uint4*)(netIn + ((b << 12) + nb0)*128 + cbase);
        const uint4* p1 = (const uint4*)(netIn + ((b << 12) + nb1)*128 + cbase);
        gb[2*j  ][0] = p0[0]; gb[2*j  ][1] = p0[1];
        gb[2*j+1][0] = p1[0]; gb[2*j+1][1] = p1[1];
      }
      #pragma unroll
      for (int j = 0; j < 10; ++j) {
        int k = h*10 + j;
        unsigned int wpair = wv[k >> 1];
        float wk = (k & 1) ? hi2f(wpair) : lo2f(wpair & 0xFFFFu);
        #pragma unroll
        for (int u = 0; u < 2; ++u) {
          uint4 uu = gb[j][u];
          acc[u*8+0] = fmaf(wk, lo2f(uu.x), acc[u*8+0]);
          acc[u*8+1] = fmaf(wk, hi2f(uu.x), acc[u*8+1]);
          acc[u*8+2] = fmaf(wk, lo2f(uu.y), acc[u*8+2]);
          acc[u*8+3] = fmaf(wk, hi2f(uu.y), acc[u*8+3]);
          acc[u*8+4] = fmaf(wk, lo2f(uu.z), acc[u*8+4]);
          acc[u*8+5] = fmaf(wk, hi2f(uu.z), acc[u*8+5]);
          acc[u*8+6] = fmaf(wk, lo2f(uu.w), acc[u*8+6]);
          acc[u*8+7] = fmaf(wk, hi2f(uu.w), acc[u*8+7]);
        }
      }
    }
    unsigned short* hb = ldsH[t];
    #pragma unroll
    for (int j = 0; j < 8; ++j) {
      unsigned int pr = ((unsigned int)f2b(acc[2*j+1]) << 16) | (unsigned int)f2b(acc[2*j]);
      *(unsigned int*)(hb + r*136 + cbase + 2*j) = pr;
    }
  }
  __syncthreads();

  // ---- stage 2: att = attsum @ Wo^T + bo -> ldsA ----
  {
    bf16x8 bw[16];
    #pragma unroll
    for (int i = 0; i < 4; ++i) {
      const unsigned short* bp = WoT + ((c*4 + i)*16 + m)*128 + qd*8;
      #pragma unroll
      for (int ks = 0; ks < 4; ++ks) bw[i*4 + ks] = *(const bf16x8*)(bp + ks*32);
    }
    bf16x8 asf[4];
    #pragma unroll
    for (int ks = 0; ks < 4; ++ks)
      asf[ks] = *(const bf16x8*)(ldsH[t] + m*136 + ks*32 + qd*8);
    f32x4 acc2[4];
    #pragma unroll
    for (int i = 0; i < 4; ++i) { f32x4 z = {0.f,0.f,0.f,0.f}; acc2[i] = z; }
    #pragma unroll
    for (int i = 0; i < 4; ++i)
      #pragma unroll
      for (int ks = 0; ks < 4; ++ks)
        acc2[i] = __builtin_amdgcn_mfma_f32_16x16x32_bf16(asf[ks], bw[i*4 + ks], acc2[i], 0, 0, 0);
    unsigned short* ab = ldsA[t];
    #pragma unroll
    for (int i = 0; i < 4; ++i) {
      int col = (c*4 + i)*16 + m;
      float bo = ldp(bos, iblk*128 + col, f32m);
      #pragma unroll
      for (int rr = 0; rr < 4; ++rr)
        ab[(qd*4 + rr)*136 + col] = f2b(acc2[i][rr] + bo);
    }
  }
  __syncthreads();

  // ---- stage 3: h = relu(net)@W0a + relu(att)@W0b + b0; relu(h) -> ldsH ----
  bf16x8 nf[4], af[4];
  {
    bf16x8 bw3[32];
    #pragma unroll
    for (int i = 0; i < 4; ++i) {
      const unsigned short* bp = W0T + ((c*4 + i)*16 + m)*256 + qd*8;
      #pragma unroll
      for (int ks = 0; ks < 4; ++ks) bw3[i*8 + ks]     = *(const bf16x8*)(bp + ks*32);
      #pragma unroll
      for (int ks = 0; ks < 4; ++ks) bw3[i*8 + 4 + ks] = *(const bf16x8*)(bp + 128 + ks*32);
    }
    const unsigned short* nrow = netIn + (r0 + m)*128;
    #pragma unroll
    for (int ks = 0; ks < 4; ++ks) nf[ks] = *(const bf16x8*)(nrow + ks*32 + qd*8);
    #pragma unroll
    for (int ks = 0; ks < 4; ++ks) af[ks] = *(const bf16x8*)(ldsA[t] + m*136 + ks*32 + qd*8);
    bf16x8 rnf[4], raf[4];
    #pragma unroll
    for (int ks = 0; ks < 4; ++ks) { rnf[ks] = relu8(nf[ks]); raf[ks] = relu8(af[ks]); }
    f32x4 acc3[4];
    #pragma unroll
    for (int i = 0; i < 4; ++i) { f32x4 z = {0.f,0.f,0.f,0.f}; acc3[i] = z; }
    #pragma unroll
    for (int i = 0; i < 4; ++i) {
      #pragma unroll
      for (int ks = 0; ks < 4; ++ks)
        acc3[i] = __builtin_amdgcn_mfma_f32_16x16x32_bf16(rnf[ks], bw3[i*8 + ks], acc3[i], 0, 0, 0);
      #pragma unroll
      for (int ks = 0; ks < 4; ++ks)
        acc3[i] = __builtin_amdgcn_mfma_f32_16x16x32_bf16(raf[ks], bw3[i*8 + 4 + ks], acc3[i], 0, 0, 0);
    }
    unsigned short* hb = ldsH[t];
    #pragma unroll
    for (int i = 0; i < 4; ++i) {
      int col = (c*4 + i)*16 + m;
      float b0v = ldp(b0s, iblk*128 + col, f32m);
      #pragma unroll
      for (int rr = 0; rr < 4; ++rr)
        hb[(qd*4 + rr)*136 + col] = f2b(fmaxf(acc3[i][rr] + b0v, 0.f));
    }
  }
  __syncthreads();

  // ---- stage 4: out = relu(h)@W1 + b1 + net@Wsa + att@Wsb (+ resid) ----
  {
    bf16x8 bw4[48];
    #pragma unroll
    for (int i = 0; i < 4; ++i) {
      const unsigned short* bp1 = W1T + ((c*4 + i)*16 + m)*128 + qd*8;
      #pragma unroll
      for (int ks = 0; ks < 4; ++ks) bw4[i*12 + ks] = *(const bf16x8*)(bp1 + ks*32);
      const unsigned short* bps = WsT + ((c*4 + i)*16 + m)*256 + qd*8;
      #pragma unroll
      for (int ks = 0; ks < 4; ++ks) bw4[i*12 + 4 + ks] = *(const bf16x8*)(bps + ks*32);
      #pragma unroll
      for (int ks = 0; ks < 4; ++ks) bw4[i*12 + 8 + ks] = *(const bf16x8*)(bps + 128 + ks*32);
    }
    bf16x8 hf[4];
    #pragma unroll
    for (int ks = 0; ks < 4; ++ks) hf[ks] = *(const bf16x8*)(ldsH[t] + m*136 + ks*32 + qd*8);
    f32x4 acc4[4];
    #pragma unroll
    for (int i = 0; i < 4; ++i) { f32x4 z = {0.f,0.f,0.f,0.f}; acc4[i] = z; }
    #pragma unroll
    for (int i = 0; i < 4; ++i) {
      #pragma unroll
      for (int ks = 0; ks < 4; ++ks)
        acc4[i] = __builtin_amdgcn_mfma_f32_16x16x32_bf16(hf[ks], bw4[i*12 + ks], acc4[i], 0, 0, 0);
      #pragma unroll
      for (int ks = 0; ks < 4; ++ks)
        acc4[i] = __builtin_amdgcn_mfma_f32_16x16x32_bf16(nf[ks], bw4[i*12 + 4 + ks], acc4[i], 0, 0, 0);
      #pragma unroll
      for (int ks = 0; ks < 4; ++ks)
        acc4[i] = __builtin_amdgcn_mfma_f32_16x16x32_bf16(af[ks], bw4[i*12 + 8 + ks], acc4[i], 0, 0, 0);
    }
    #pragma unroll
    for (int i = 0; i < 4; ++i) {
      int col = (c*4 + i)*16 + m;
      float b1v = ldp(b1s, iblk*128 + col, f32m);
      #pragma unroll
      for (int rr = 0; rr < 4; ++rr) {
        int grow2 = r0 + qd*4 + rr;
        float v = acc4[i][rr] + b1v;
        if (hasResid) v += b2f(netIn[grow2*128 + col]);
        netOut[grow2*128 + col] = f2b(v);
      }
    }
  }
}

// ---------------- final: out = net @ W_c + b_c (dtype per flag) ----------------
__global__ __launch_bounds__(256, 1) void k_final(const unsigned short* __restrict__ netIn,
                                                  const unsigned short* __restrict__ WcT,
                                                  const void* __restrict__ bcv,
                                                  const int* __restrict__ flagp,
                                                  void* __restrict__ out){
  int tid = threadIdx.x; int w = tid >> 6, lane = tid & 63;
  int f32m = *flagp;
  int t = w >> 1, c = w & 1;
  int r0 = blockIdx.x*32 + t*16;
  int m = lane & 15, qd = lane >> 4;
  bf16x8 bw[16];
  #pragma unroll
  for (int i = 0; i < 4; ++i) {
    const unsigned short* bp = WcT + ((c*4 + i)*16 + m)*128 + qd*8;
    #pragma unroll
    for (int ks = 0; ks < 4; ++ks) bw[i*4 + ks] = *(const bf16x8*)(bp + ks*32);
  }
  bf16x8 nf[4];
  #pragma unroll
  for (int ks = 0; ks < 4; ++ks)
    nf[ks] = *(const bf16x8*)(netIn + (r0 + m)*128 + ks*32 + qd*8);
  f32x4 acc[4];
  #pragma unroll
  for (int i = 0; i < 4; ++i) { f32x4 z = {0.f,0.f,0.f,0.f}; acc[i] = z; }
  #pragma unroll
  for (int i = 0; i < 4; ++i)
    #pragma unroll
    for (int ks = 0; ks < 4; ++ks)
      acc[i] = __builtin_amdgcn_mfma_f32_16x16x32_bf16(nf[ks], bw[i*4 + ks], acc[i], 0, 0, 0);
  if (f32m) {
    float* o = (float*)out;
    #pragma unroll
    for (int i = 0; i < 4; ++i) {
      int col = (c*4 + i)*16 + m;
      float bcf = ldp(bcv, col, 1);
      #pragma unroll
      for (int rr = 0; rr < 4; ++rr)
        o[(r0 + qd*4 + rr)*128 + col] = acc[i][rr] + bcf;
    }
  } else {
    unsigned short* o = (unsigned short*)out;
    #pragma unroll
    for (int i = 0; i < 4; ++i) {
      int col = (c*4 + i)*16 + m;
      float bcf = ldp(bcv, col, 0);
      #pragma unroll
      for (int rr = 0; rr < 4; ++rr)
        o[(r0 + qd*4 + rr)*128 + col] = f2b(acc[i][rr] + bcf);
    }
  }
}

// ---------------- host launch ----------------
extern "C" void kernel_launch(void* const* d_in, const int* in_sizes, int n_in,
                              void* d_out, int out_size, void* d_ws, size_t ws_size,
                              hipStream_t stream){
  const void* p    = d_in[0];
  const void* Wpos = d_in[1];
  const void* bpos = d_in[2];
  const void* W0   = d_in[3];
  const void* b0   = d_in[4];
  const void* W1   = d_in[5];
  const void* b1   = d_in[6];
  const void* Ws   = d_in[7];
  const void* Wc_  = d_in[8];
  const void* bc_  = d_in[9];
  const void* Wo   = d_in[10];
  const void* bo   = d_in[11];
  const void* WC   = d_in[12];
  const void* bC   = d_in[13];

  char* ws = (char*)d_ws;
  int*            flag   = (int*)(ws + 0);                    //      256 B (padded)
  float4*         pf4    = (float4*)(ws + 256);               //   524288 B
  unsigned short* idx16  = (unsigned short*)(ws + 524544);    //  1310720 B
  unsigned short* wsoftb = (unsigned short*)(ws + 1835264);   //  7864320 B
  unsigned short* netA   = (unsigned short*)(ws + 9699584);   //  8388608 B
  unsigned short* wT     = (unsigned short*)(ws + 18088192);  //  1212416 B (total ~19.3 MB)

  k_detect     <<<dim3(1),     dim3(64),  0, stream>>>((const unsigned short*)Wpos, flag);
  k_prep_points<<<dim3(128),   dim3(256), 0, stream>>>(p, flag, pf4);
  k_net0       <<<dim3(16384), dim3(256), 0, stream>>>(pf4, Wpos, bpos, flag, netA);
  k_transpose  <<<dim3(2368),  dim3(256), 0, stream>>>(W0, W1, Ws, Wo, WC, flag, wT);
  k_knn        <<<dim3(512),   dim3(256), 0, stream>>>(pf4, Wc_, bc_, flag, idx16, wsoftb);

  unsigned short* a   = netA;
  unsigned short* bpt = (unsigned short*)d_out;   // d_out as bf16 ping-pong scratch
  for (int i = 0; i < 6; ++i) {
    k_block<<<dim3(1024), dim3(256), 0, stream>>>(a, bpt, idx16, wsoftb, wT,
                                                  b0, b1, bo, flag, i, (i > 0) ? 1 : 0);
    unsigned short* t = a; a = bpt; bpt = t;
  }
  // 6 swaps: final net is in netA (== a)
  k_final<<<dim3(1024), dim3(256), 0, stream>>>(a, wT + 589824, bC, flag, d_out);
}

// Round 11
// 714.397 us; speedup vs baseline: 1.1465x; 1.0454x over previous
//
#include <hip/hip_runtime.h>
#include <hip/hip_bf16.h>
#include <math.h>

#define BB 8
#define TT 4096
#define HHD 128
#define NBK 6
#define KNN 20
#define BT (BB*TT)

typedef __attribute__((ext_vector_type(8))) short bf16x8;
typedef __attribute__((ext_vector_type(4))) float f32x4;

__device__ __forceinline__ float b2f(unsigned short u){
  return __uint_as_float(((unsigned int)u) << 16);
}
__device__ __forceinline__ unsigned short f2b(float f){
  unsigned int x = __float_as_uint(f);
  unsigned int r = (x + 0x7fffu + ((x >> 16) & 1u)) >> 16;   // RTNE
  return (unsigned short)r;
}
// dtype-agnostic parameter load: f32m=1 -> buffer is float32, else bf16
__device__ __forceinline__ float ldp(const void* base, int i, int f32m){
  return f32m ? ((const float*)base)[i] : b2f(((const unsigned short*)base)[i]);
}
__device__ __forceinline__ float lo2f(unsigned int u){ return __uint_as_float(u << 16); }
__device__ __forceinline__ float hi2f(unsigned int u){ return __uint_as_float(u & 0xffff0000u); }
__device__ __forceinline__ unsigned int relu2(unsigned int u){
  unsigned int s = u & 0x80008000u;
  unsigned int m = s | (s - (s >> 15));
  return u & ~m;
}
__device__ __forceinline__ bf16x8 relu8(bf16x8 x){
  union { bf16x8 v; unsigned int u[4]; } t; t.v = x;
  t.u[0] = relu2(t.u[0]); t.u[1] = relu2(t.u[1]);
  t.u[2] = relu2(t.u[2]); t.u[3] = relu2(t.u[3]);
  return t.v;
}

// ---------------- dtype detector ----------------
__global__ void k_detect(const unsigned short* __restrict__ wpos_raw, int* __restrict__ flag){
  if (threadIdx.x == 0 && blockIdx.x == 0) {
    int cnt = 0;
    for (int i = 0; i < 384; ++i) {
      unsigned int e = (wpos_raw[i] >> 7) & 0xFFu;
      if (e >= 0x90u) cnt++;
    }
    *flag = (cnt > 10) ? 1 : 0;
  }
}

// ---------------- prep: p -> float4 (x,y,z,|p|^2) ----------------
__global__ __launch_bounds__(256) void k_prep_points(const void* __restrict__ p,
                                                     const int* __restrict__ flagp,
                                                     float4* __restrict__ pf4){
  int r = blockIdx.x*256 + threadIdx.x;
  if (r >= BT) return;
  int f32m = *flagp;
  float x = ldp(p, r*3+0, f32m), y = ldp(p, r*3+1, f32m), z = ldp(p, r*3+2, f32m);
  float sq = __fadd_rn(__fadd_rn(__fmul_rn(x,x), __fmul_rn(y,y)), __fmul_rn(z,z));
  pf4[r] = make_float4(x, y, z, sq);
}

// ---------------- net0 = p @ W_pos + b_pos  (bf16 out) ----------------
__global__ __launch_bounds__(256) void k_net0(const float4* __restrict__ pf4,
                                              const void* __restrict__ Wpos,
                                              const void* __restrict__ bpos,
                                              const int* __restrict__ flagp,
                                              unsigned short* __restrict__ netA){
  int t = blockIdx.x*256 + threadIdx.x;   // over BT*128
  int f32m = *flagp;
  int c = t & 127, r = t >> 7;
  float4 q = pf4[r];
  float v = ldp(bpos, c, f32m);
  v = fmaf(q.x, ldp(Wpos, c,       f32m), v);
  v = fmaf(q.y, ldp(Wpos, 128 + c, f32m), v);
  v = fmaf(q.z, ldp(Wpos, 256 + c, f32m), v);
  netA[t] = f2b(v);
}

// ---------------- transpose all weights to [N][K] bf16 ----------------
// layout in wT (shorts): W0T 6*32768 | W1T 6*16384 | WsT 6*32768 | WoT 6*16384 | WcT 16384
__global__ __launch_bounds__(256) void k_transpose(const void* __restrict__ W0,
                                                   const void* __restrict__ W1,
                                                   const void* __restrict__ Ws,
                                                   const void* __restrict__ Wo,
                                                   const void* __restrict__ Wc,
                                                   const int* __restrict__ flagp,
                                                   unsigned short* __restrict__ wT){
  int t = blockIdx.x*256 + threadIdx.x;
  int f32m = *flagp;
  if (t < 196608) {                    // W0T: per block [128][256]
    int i = t >> 15; int rem = t & 32767; int n = rem >> 8; int k = rem & 255;
    wT[t] = f2b(ldp(W0, i*32768 + k*128 + n, f32m));
  } else if (t < 294912) {             // W1T: [128][128]
    int u = t - 196608; int i = u >> 14; int rem = u & 16383; int n = rem >> 7; int k = rem & 127;
    wT[t] = f2b(ldp(W1, i*16384 + k*128 + n, f32m));
  } else if (t < 491520) {             // WsT: [128][256]
    int u = t - 294912; int i = u >> 15; int rem = u & 32767; int n = rem >> 8; int k = rem & 255;
    wT[t] = f2b(ldp(Ws, i*32768 + k*128 + n, f32m));
  } else if (t < 589824) {             // WoT: [128][128]
    int u = t - 491520; int i = u >> 14; int rem = u & 16383; int n = rem >> 7; int k = rem & 127;
    wT[t] = f2b(ldp(Wo, i*16384 + k*128 + n, f32m));
  } else if (t < 606208) {             // WcT: [128][128]
    int u = t - 589824; int n = u >> 7; int k = u & 127;
    wT[t] = f2b(ldp(Wc, k*128 + n, f32m));
  }
}

// sorted ascending insert into (ld,li)[20], strict '<' keeps earliest index on ties
#define INS(act, dv, iv) do { bool A_ = (act); float D_ = (dv); int I_ = (iv);        \
  _Pragma("unroll")                                                                    \
  for (int j = 19; j >= 1; --j) {                                                      \
    bool cj = A_ && (D_ < ld[j]); bool cm = A_ && (D_ < ld[j-1]);                      \
    ld[j] = cj ? (cm ? ld[j-1] : D_) : ld[j];                                          \
    li[j] = cj ? (cm ? li[j-1] : I_) : li[j];                                          \
  }                                                                                    \
  { bool c0 = A_ && (D_ < ld[0]); ld[0] = c0 ? D_ : ld[0]; li[0] = c0 ? I_ : li[0]; } \
} while(0)

// ---------------- KNN: 4 waves/query-group, partitioned candidates ----------------
// (round-4/6 proven version, unchanged)
__global__ __launch_bounds__(256) void k_knn(const float4* __restrict__ pf4,
                                             const void* __restrict__ Wc,
                                             const void* __restrict__ bc,
                                             const int* __restrict__ flagp,
                                             unsigned short* __restrict__ idx16,
                                             unsigned short* __restrict__ wsoftb){
  __shared__ char smem[40960];
  float4* tile = (float4*)smem;                 // [4][256] float4 = 16 KB (scan phase)
  float*  lsd  = (float*)smem;                  // [256][20] = 20 KB (merge phase)
  int*    lsi  = (int*)(smem + 20480);          // [256][20] = 20 KB

  int tid  = threadIdx.x;
  int part = tid >> 6, lane = tid & 63;
  int rq   = blockIdx.x*64 + lane;              // query row (512 blocks x 64)
  int b    = rq >> 12;
  int f32m = *flagp;
  float4 q = pf4[rq];

  float ld[20]; int li[20];
  #pragma unroll
  for (int j = 0; j < 20; ++j) { ld[j] = 3.0e38f; li[j] = 0; }
  float thresh = 3.0e38f;
  float bd0=0.f,bd1=0.f,bd2=0.f,bd3=0.f; int bi0=0,bi1=0,bi2=0,bi3=0; int cnt=0;

  for (int ch = 0; ch < 4; ++ch) {
    __syncthreads();
    {
      const float4* src = pf4 + (b << 12) + part*1024 + ch*256;
      tile[part*256 + lane      ] = src[lane      ];
      tile[part*256 + lane +  64] = src[lane +  64];
      tile[part*256 + lane + 128] = src[lane + 128];
      tile[part*256 + lane + 192] = src[lane + 192];
    }
    __syncthreads();
    int baseI = part*1024 + ch*256;
    for (int j = 0; j < 256; ++j) {
      float4 pt = tile[part*256 + j];
      float dot = __fadd_rn(__fadd_rn(__fmul_rn(q.x,pt.x), __fmul_rn(q.y,pt.y)),
                            __fmul_rn(q.z,pt.z));
      float d2  = __fsub_rn(__fadd_rn(q.w, pt.w), __fmul_rn(2.0f, dot));
      bool take = d2 < thresh;       // thresh is upper bound of true 20th-best: never drops a keeper
      int  gi   = baseI + j;
      bool t0 = take && (cnt == 0); bd0 = t0 ? d2 : bd0; bi0 = t0 ? gi : bi0;
      bool t1 = take && (cnt == 1); bd1 = t1 ? d2 : bd1; bi1 = t1 ? gi : bi1;
      bool t2 = take && (cnt == 2); bd2 = t2 ? d2 : bd2; bi2 = t2 ? gi : bi2;
      bool t3 = take && (cnt == 3); bd3 = t3 ? d2 : bd3; bi3 = t3 ? gi : bi3;
      cnt += take ? 1 : 0;
      if (__ballot(cnt >= 4)) {      // wave-uniform branch
        INS(cnt > 0, bd0, bi0); INS(cnt > 1, bd1, bi1);
        INS(cnt > 2, bd2, bi2); INS(cnt > 3, bd3, bi3);
        cnt = 0; thresh = ld[19];
      }
    }
  }
  INS(cnt > 0, bd0, bi0); INS(cnt > 1, bd1, bi1);
  INS(cnt > 2, bd2, bi2); INS(cnt > 3, bd3, bi3);

  __syncthreads();                   // scan done; tile region reused as lsd/lsi
  #pragma unroll
  for (int j = 0; j < 20; ++j) { lsd[tid*20 + j] = ld[j]; lsi[tid*20 + j] = li[j]; }
  __syncthreads();

  if (tid < 64) {                    // lane q of wave 0 merges query q's 4 lists
    int p0 = tid*20, p1 = (64+tid)*20, p2 = (128+tid)*20, p3 = (192+tid)*20;
    int i0=0, i1=0, i2=0, i3=0;
    float dis[20]; int outi[20];
    #pragma unroll 4
    for (int o = 0; o < 20; ++o) {
      float d0 = lsd[p0+i0], d1 = lsd[p1+i1], d2v = lsd[p2+i2], d3 = lsd[p3+i3];
      float bd = d0; int sel = 0;
      if (d1  < bd) { bd = d1;  sel = 1; }    // strict <: lowest partition wins ties
      if (d2v < bd) { bd = d2v; sel = 2; }
      if (d3  < bd) { bd = d3;  sel = 3; }
      int bi = (sel==0) ? lsi[p0+i0] : (sel==1) ? lsi[p1+i1] : (sel==2) ? lsi[p2+i2] : lsi[p3+i3];
      i0 += (sel==0); i1 += (sel==1); i2 += (sel==2); i3 += (sel==3);
      dis[o] = sqrtf(fmaxf(bd, 1e-12f));
      outi[o] = bi;
    }
    // ---- fused attention softmax weights, all 6 blocks ----
    float nx[20], ny[20], nz[20];
    #pragma unroll 4
    for (int k = 0; k < 20; ++k) {
      idx16[rq*20 + k] = (unsigned short)outi[k];
      float4 pp = pf4[(b << 12) + outi[k]];
      nx[k] = pp.x; ny[k] = pp.y; nz[k] = pp.z;
    }
    for (int i = 0; i < NBK; ++i) {
      float w0 = ldp(Wc,i*7+0,f32m), w1 = ldp(Wc,i*7+1,f32m), w2 = ldp(Wc,i*7+2,f32m);
      float w3 = ldp(Wc,i*7+3,f32m), w4 = ldp(Wc,i*7+4,f32m), w5 = ldp(Wc,i*7+5,f32m);
      float w6 = ldp(Wc,i*7+6,f32m);
      float bci = ldp(bc,i,f32m);
      float s[20]; float mx = -3.0e38f;
      #pragma unroll
      for (int k = 0; k < 20; ++k) {
        float v = bci;
        v = fmaf(dis[k], w0, v);
        v = fmaf(nx[k], w1, v); v = fmaf(ny[k], w2, v); v = fmaf(nz[k], w3, v);
        v = fmaf(q.x, w4, v);  v = fmaf(q.y, w5, v);  v = fmaf(q.z, w6, v);
        s[k] = v; mx = fmaxf(mx, v);
      }
      float sum = 0.f;
      #pragma unroll
      for (int k = 0; k < 20; ++k) { float e = __expf(s[k] - mx); s[k] = e; sum += e; }
      float inv = 1.0f / sum;
      #pragma unroll
      for (int k = 0; k < 20; ++k) wsoftb[(rq*6 + i)*20 + k] = f2b(s[k]*inv);
    }
  }
}

// ---------------- one resnet block (fused gather+attention+GEMMs) ----------------
// R6 proven structure (1024 blocks x 32 rows, col-split, 4 barriers) + batched
// gather: idx/weight words preloaded into registers so the 40 gather loads have
// no serial idx->load dependency (MLP via unroll-4 window). VGPR ~110 < 128 so
// occupancy (4 blocks/CU) is unchanged. Accumulation order identical to R6.
__global__ __launch_bounds__(256) void k_block(const unsigned short* __restrict__ netIn,
                                               unsigned short* __restrict__ netOut,
                                               const unsigned short* __restrict__ idx16,
                                               const unsigned short* __restrict__ wsoftb,
                                               const unsigned short* __restrict__ wT,
                                               const void* __restrict__ b0s,
                                               const void* __restrict__ b1s,
                                               const void* __restrict__ bos,
                                               const int* __restrict__ flagp,
                                               int iblk, int hasResid){
  __shared__ unsigned short ldsA[2][16*136];
  __shared__ unsigned short ldsH[2][16*136];
  int tid = threadIdx.x;
  int f32m = *flagp;
  int w = tid >> 6, lane = tid & 63;
  int t = w >> 1;            // row tile 0/1
  int c = w & 1;             // col half 0/1
  int b  = blockIdx.x & 7;   // XCD swizzle: gathers stay within one batch's net
  int r0 = (b << 12) + ((blockIdx.x >> 3) << 5) + (t << 4);
  const unsigned short* W0T = wT + iblk*32768;
  const unsigned short* W1T = wT + 196608 + iblk*16384;
  const unsigned short* WsT = wT + 294912 + iblk*32768;
  const unsigned short* WoT = wT + 491520 + iblk*16384;
  int m = lane & 15, qd = lane >> 4;

  // ---- stage 1: attsum[r][cols c*64+cg*16 .. +16] = sum_k w * netIn[idx_k] ----
  {
    int r = lane >> 2, cg = lane & 3;
    int grow = r0 + r;
    int cbase = c*64 + cg*16;
    const unsigned int* ip = (const unsigned int*)(idx16 + grow*20);
    const unsigned int* wp = (const unsigned int*)(wsoftb + (grow*6 + iblk)*20);
    unsigned int iv[10], wv[10];
    #pragma unroll
    for (int j = 0; j < 10; ++j) iv[j] = ip[j];
    #pragma unroll
    for (int j = 0; j < 10; ++j) wv[j] = wp[j];
    float acc[16];
    #pragma unroll
    for (int j = 0; j < 16; ++j) acc[j] = 0.f;
    #pragma unroll 4
    for (int k = 0; k < 20; ++k) {
      unsigned int pair = iv[k >> 1];
      int nb = (int)((k & 1) ? (pair >> 16) : pair) & 4095;
      unsigned int wpair = wv[k >> 1];
      float wk = (k & 1) ? hi2f(wpair) : lo2f(wpair);
      const uint4* np_ = (const uint4*)(netIn + ((b << 12) + nb)*128 + cbase);
      #pragma unroll
      for (int u = 0; u < 2; ++u) {
        uint4 uu = np_[u];
        acc[u*8+0] = fmaf(wk, lo2f(uu.x), acc[u*8+0]);
        acc[u*8+1] = fmaf(wk, hi2f(uu.x), acc[u*8+1]);
        acc[u*8+2] = fmaf(wk, lo2f(uu.y), acc[u*8+2]);
        acc[u*8+3] = fmaf(wk, hi2f(uu.y), acc[u*8+3]);
        acc[u*8+4] = fmaf(wk, lo2f(uu.z), acc[u*8+4]);
        acc[u*8+5] = fmaf(wk, hi2f(uu.z), acc[u*8+5]);
        acc[u*8+6] = fmaf(wk, lo2f(uu.w), acc[u*8+6]);
        acc[u*8+7] = fmaf(wk, hi2f(uu.w), acc[u*8+7]);
      }
    }
    unsigned short* hb = ldsH[t];
    #pragma unroll
    for (int j = 0; j < 8; ++j) {
      unsigned int pr = ((unsigned int)f2b(acc[2*j+1]) << 16) | (unsigned int)f2b(acc[2*j]);
      *(unsigned int*)(hb + r*136 + cbase + 2*j) = pr;
    }
  }
  __syncthreads();

  // ---- stage 2: att = attsum @ Wo^T + bo -> ldsA (4 col-tiles per wave) ----
  {
    bf16x8 asf[4];
    #pragma unroll
    for (int ks = 0; ks < 4; ++ks)
      asf[ks] = *(const bf16x8*)(ldsH[t] + m*136 + ks*32 + qd*8);
    f32x4 acc2[4];
    #pragma unroll
    for (int i = 0; i < 4; ++i) { f32x4 z = {0.f,0.f,0.f,0.f}; acc2[i] = z; }
    #pragma unroll
    for (int i = 0; i < 4; ++i) {
      int cti = c*4 + i;
      const unsigned short* bp = WoT + (cti*16 + m)*128 + qd*8;
      #pragma unroll
      for (int ks = 0; ks < 4; ++ks)
        acc2[i] = __builtin_amdgcn_mfma_f32_16x16x32_bf16(asf[ks], *(const bf16x8*)(bp + ks*32), acc2[i], 0, 0, 0);
    }
    unsigned short* ab = ldsA[t];
    #pragma unroll
    for (int i = 0; i < 4; ++i) {
      int col = (c*4 + i)*16 + m;
      float bo = ldp(bos, iblk*128 + col, f32m);
      #pragma unroll
      for (int rr = 0; rr < 4; ++rr)
        ab[(qd*4 + rr)*136 + col] = f2b(acc2[i][rr] + bo);
    }
  }
  __syncthreads();

  // ---- stage 3: h = relu(net)@W0a + relu(att)@W0b + b0; relu(h) -> ldsH ----
  bf16x8 nf[4], af[4];
  {
    const unsigned short* nrow = netIn + (r0 + m)*128;
    #pragma unroll
    for (int ks = 0; ks < 4; ++ks) nf[ks] = *(const bf16x8*)(nrow + ks*32 + qd*8);
    #pragma unroll
    for (int ks = 0; ks < 4; ++ks) af[ks] = *(const bf16x8*)(ldsA[t] + m*136 + ks*32 + qd*8);
    bf16x8 rnf[4], raf[4];
    #pragma unroll
    for (int ks = 0; ks < 4; ++ks) { rnf[ks] = relu8(nf[ks]); raf[ks] = relu8(af[ks]); }
    f32x4 acc3[4];
    #pragma unroll
    for (int i = 0; i < 4; ++i) { f32x4 z = {0.f,0.f,0.f,0.f}; acc3[i] = z; }
    #pragma unroll
    for (int i = 0; i < 4; ++i) {
      int cti = c*4 + i;
      const unsigned short* bp = W0T + (cti*16 + m)*256 + qd*8;
      #pragma unroll
      for (int ks = 0; ks < 4; ++ks)
        acc3[i] = __builtin_amdgcn_mfma_f32_16x16x32_bf16(rnf[ks], *(const bf16x8*)(bp + ks*32), acc3[i], 0, 0, 0);
      #pragma unroll
      for (int ks = 0; ks < 4; ++ks)
        acc3[i] = __builtin_amdgcn_mfma_f32_16x16x32_bf16(raf[ks], *(const bf16x8*)(bp + 128 + ks*32), acc3[i], 0, 0, 0);
    }
    unsigned short* hb = ldsH[t];
    #pragma unroll
    for (int i = 0; i < 4; ++i) {
      int col = (c*4 + i)*16 + m;
      float b0v = ldp(b0s, iblk*128 + col, f32m);
      #pragma unroll
      for (int rr = 0; rr < 4; ++rr)
        hb[(qd*4 + rr)*136 + col] = f2b(fmaxf(acc3[i][rr] + b0v, 0.f));
    }
  }
  __syncthreads();

  // ---- stage 4: out = relu(h)@W1 + b1 + net@Wsa + att@Wsb (+ resid) ----
  {
    bf16x8 hf[4];
    #pragma unroll
    for (int ks = 0; ks < 4; ++ks) hf[ks] = *(const bf16x8*)(ldsH[t] + m*136 + ks*32 + qd*8);
    f32x4 acc4[4];
    #pragma unroll
    for (int i = 0; i < 4; ++i) { f32x4 z = {0.f,0.f,0.f,0.f}; acc4[i] = z; }
    #pragma unroll
    for (int i = 0; i < 4; ++i) {
      int cti = c*4 + i;
      const unsigned short* bp1 = W1T + (cti*16 + m)*128 + qd*8;
      #pragma unroll
      for (int ks = 0; ks < 4; ++ks)
        acc4[i] = __builtin_amdgcn_mfma_f32_16x16x32_bf16(hf[ks], *(const bf16x8*)(bp1 + ks*32), acc4[i], 0, 0, 0);
      const unsigned short* bps = WsT + (cti*16 + m)*256 + qd*8;
      #pragma unroll
      for (int ks = 0; ks < 4; ++ks)
        acc4[i] = __builtin_amdgcn_mfma_f32_16x16x32_bf16(nf[ks], *(const bf16x8*)(bps + ks*32), acc4[i], 0, 0, 0);
      #pragma unroll
      for (int ks = 0; ks < 4; ++ks)
        acc4[i] = __builtin_amdgcn_mfma_f32_16x16x32_bf16(af[ks], *(const bf16x8*)(bps + 128 + ks*32), acc4[i], 0, 0, 0);
    }
    #pragma unroll
    for (int i = 0; i < 4; ++i) {
      int col = (c*4 + i)*16 + m;
      float b1v = ldp(b1s, iblk*128 + col, f32m);
      #pragma unroll
      for (int rr = 0; rr < 4; ++rr) {
        int grow2 = r0 + qd*4 + rr;
        float v = acc4[i][rr] + b1v;
        if (hasResid) v += b2f(netIn[grow2*128 + col]);
        netOut[grow2*128 + col] = f2b(v);
      }
    }
  }
}

// ---------------- final: out = net @ W_c + b_c (dtype per flag) ----------------
__global__ __launch_bounds__(256) void k_final(const unsigned short* __restrict__ netIn,
                                               const unsigned short* __restrict__ WcT,
                                               const void* __restrict__ bcv,
                                               const int* __restrict__ flagp,
                                               void* __restrict__ out){
  int tid = threadIdx.x; int w = tid >> 6, lane = tid & 63;
  int f32m = *flagp;
  int t = w >> 1, c = w & 1;
  int r0 = blockIdx.x*32 + t*16;
  int m = lane & 15, qd = lane >> 4;
  bf16x8 nf[4];
  #pragma unroll
  for (int ks = 0; ks < 4; ++ks)
    nf[ks] = *(const bf16x8*)(netIn + (r0 + m)*128 + ks*32 + qd*8);
  f32x4 acc[4];
  #pragma unroll
  for (int i = 0; i < 4; ++i) { f32x4 z = {0.f,0.f,0.f,0.f}; acc[i] = z; }
  #pragma unroll
  for (int i = 0; i < 4; ++i) {
    int cti = c*4 + i;
    const unsigned short* bp = WcT + (cti*16 + m)*128 + qd*8;
    #pragma unroll
    for (int ks = 0; ks < 4; ++ks)
      acc[i] = __builtin_amdgcn_mfma_f32_16x16x32_bf16(nf[ks], *(const bf16x8*)(bp + ks*32), acc[i], 0, 0, 0);
  }
  if (f32m) {
    float* o = (float*)out;
    #pragma unroll
    for (int i = 0; i < 4; ++i) {
      int col = (c*4 + i)*16 + m;
      float bcf = ldp(bcv, col, 1);
      #pragma unroll
      for (int rr = 0; rr < 4; ++rr)
        o[(r0 + qd*4 + rr)*128 + col] = acc[i][rr] + bcf;
    }
  } else {
    unsigned short* o = (unsigned short*)out;
    #pragma unroll
    for (int i = 0; i < 4; ++i) {
      int col = (c*4 + i)*16 + m;
      float bcf = ldp(bcv, col, 0);
      #pragma unroll
      for (int rr = 0; rr < 4; ++rr)
        o[(r0 + qd*4 + rr)*128 + col] = f2b(acc[i][rr] + bcf);
    }
  }
}

// ---------------- host launch ----------------
extern "C" void kernel_launch(void* const* d_in, const int* in_sizes, int n_in,
                              void* d_out, int out_size, void* d_ws, size_t ws_size,
                              hipStream_t stream){
  const void* p    = d_in[0];
  const void* Wpos = d_in[1];
  const void* bpos = d_in[2];
  const void* W0   = d_in[3];
  const void* b0   = d_in[4];
  const void* W1   = d_in[5];
  const void* b1   = d_in[6];
  const void* Ws   = d_in[7];
  const void* Wc_  = d_in[8];
  const void* bc_  = d_in[9];
  const void* Wo   = d_in[10];
  const void* bo   = d_in[11];
  const void* WC   = d_in[12];
  const void* bC   = d_in[13];

  char* ws = (char*)d_ws;
  int*            flag   = (int*)(ws + 0);                    //      256 B (padded)
  float4*         pf4    = (float4*)(ws + 256);               //   524288 B
  unsigned short* idx16  = (unsigned short*)(ws + 524544);    //  1310720 B
  unsigned short* wsoftb = (unsigned short*)(ws + 1835264);   //  7864320 B
  unsigned short* netA   = (unsigned short*)(ws + 9699584);   //  8388608 B
  unsigned short* wT     = (unsigned short*)(ws + 18088192);  //  1212416 B (total ~19.3 MB)

  k_detect     <<<dim3(1),     dim3(64),  0, stream>>>((const unsigned short*)Wpos, flag);
  k_prep_points<<<dim3(128),   dim3(256), 0, stream>>>(p, flag, pf4);
  k_net0       <<<dim3(16384), dim3(256), 0, stream>>>(pf4, Wpos, bpos, flag, netA);
  k_transpose  <<<dim3(2368),  dim3(256), 0, stream>>>(W0, W1, Ws, Wo, WC, flag, wT);
  k_knn        <<<dim3(512),   dim3(256), 0, stream>>>(pf4, Wc_, bc_, flag, idx16, wsoftb);

  unsigned short* a   = netA;
  unsigned short* bpt = (unsigned short*)d_out;   // d_out as bf16 ping-pong scratch
  for (int i = 0; i < 6; ++i) {
    k_block<<<dim3(1024), dim3(256), 0, stream>>>(a, bpt, idx16, wsoftb, wT,
                                                  b0, b1, bo, flag, i, (i > 0) ? 1 : 0);
    unsigned short* t = a; a = bpt; bpt = t;
  }
  // 6 swaps: final net is in netA (== a)
  k_final<<<dim3(1024), dim3(256), 0, stream>>>(a, wT + 589824, bC, flag, d_out);
}

// Round 12
// 695.082 us; speedup vs baseline: 1.1784x; 1.0278x over previous
//
#include <hip/hip_runtime.h>
#include <hip/hip_bf16.h>
#include <math.h>

#define BB 8
#define TT 4096
#define HHD 128
#define NBK 6
#define KNN 20
#define BT (BB*TT)

typedef __attribute__((ext_vector_type(8))) short bf16x8;
typedef __attribute__((ext_vector_type(4))) float f32x4;

__device__ __forceinline__ float b2f(unsigned short u){
  return __uint_as_float(((unsigned int)u) << 16);
}
__device__ __forceinline__ unsigned short f2b(float f){
  unsigned int x = __float_as_uint(f);
  unsigned int r = (x + 0x7fffu + ((x >> 16) & 1u)) >> 16;   // RTNE
  return (unsigned short)r;
}
// dtype-agnostic parameter load: f32m=1 -> buffer is float32, else bf16
__device__ __forceinline__ float ldp(const void* base, int i, int f32m){
  return f32m ? ((const float*)base)[i] : b2f(((const unsigned short*)base)[i]);
}
__device__ __forceinline__ float lo2f(unsigned int u){ return __uint_as_float(u << 16); }
__device__ __forceinline__ float hi2f(unsigned int u){ return __uint_as_float(u & 0xffff0000u); }
__device__ __forceinline__ unsigned int relu2(unsigned int u){
  unsigned int s = u & 0x80008000u;
  unsigned int m = s | (s - (s >> 15));
  return u & ~m;
}
__device__ __forceinline__ bf16x8 relu8(bf16x8 x){
  union { bf16x8 v; unsigned int u[4]; } t; t.v = x;
  t.u[0] = relu2(t.u[0]); t.u[1] = relu2(t.u[1]);
  t.u[2] = relu2(t.u[2]); t.u[3] = relu2(t.u[3]);
  return t.v;
}

// ---------------- dtype detector (64-lane parallel) ----------------
__global__ void k_detect(const unsigned short* __restrict__ wpos_raw, int* __restrict__ flag){
  int lane = threadIdx.x;   // 64 threads
  int cnt = 0;
  for (int i = lane; i < 384; i += 64) {
    unsigned int e = (wpos_raw[i] >> 7) & 0xFFu;
    if (e >= 0x90u) cnt++;
  }
  #pragma unroll
  for (int off = 32; off > 0; off >>= 1) cnt += __shfl_down(cnt, off);
  if (lane == 0) *flag = (cnt > 10) ? 1 : 0;
}

// ---------------- prep: p -> float4 (x,y,z,|p|^2) ----------------
__global__ __launch_bounds__(256) void k_prep_points(const void* __restrict__ p,
                                                     const int* __restrict__ flagp,
                                                     float4* __restrict__ pf4){
  int r = blockIdx.x*256 + threadIdx.x;
  if (r >= BT) return;
  int f32m = *flagp;
  float x = ldp(p, r*3+0, f32m), y = ldp(p, r*3+1, f32m), z = ldp(p, r*3+2, f32m);
  float sq = __fadd_rn(__fadd_rn(__fmul_rn(x,x), __fmul_rn(y,y)), __fmul_rn(z,z));
  pf4[r] = make_float4(x, y, z, sq);
}

// ---------------- net0 = p @ W_pos + b_pos  (bf16 out) ----------------
__global__ __launch_bounds__(256) void k_net0(const float4* __restrict__ pf4,
                                              const void* __restrict__ Wpos,
                                              const void* __restrict__ bpos,
                                              const int* __restrict__ flagp,
                                              unsigned short* __restrict__ netA){
  int t = blockIdx.x*256 + threadIdx.x;   // over BT*128
  int f32m = *flagp;
  int c = t & 127, r = t >> 7;
  float4 q = pf4[r];
  float v = ldp(bpos, c, f32m);
  v = fmaf(q.x, ldp(Wpos, c,       f32m), v);
  v = fmaf(q.y, ldp(Wpos, 128 + c, f32m), v);
  v = fmaf(q.z, ldp(Wpos, 256 + c, f32m), v);
  netA[t] = f2b(v);
}

// ---------------- transpose all weights to [N][K] bf16 ----------------
// layout in wT (shorts): W0T 6*32768 | W1T 6*16384 | WsT 6*32768 | WoT 6*16384 | WcT 16384
__global__ __launch_bounds__(256) void k_transpose(const void* __restrict__ W0,
                                                   const void* __restrict__ W1,
                                                   const void* __restrict__ Ws,
                                                   const void* __restrict__ Wo,
                                                   const void* __restrict__ Wc,
                                                   const int* __restrict__ flagp,
                                                   unsigned short* __restrict__ wT){
  int t = blockIdx.x*256 + threadIdx.x;
  int f32m = *flagp;
  if (t < 196608) {                    // W0T: per block [128][256]
    int i = t >> 15; int rem = t & 32767; int n = rem >> 8; int k = rem & 255;
    wT[t] = f2b(ldp(W0, i*32768 + k*128 + n, f32m));
  } else if (t < 294912) {             // W1T: [128][128]
    int u = t - 196608; int i = u >> 14; int rem = u & 16383; int n = rem >> 7; int k = rem & 127;
    wT[t] = f2b(ldp(W1, i*16384 + k*128 + n, f32m));
  } else if (t < 491520) {             // WsT: [128][256]
    int u = t - 294912; int i = u >> 15; int rem = u & 32767; int n = rem >> 8; int k = rem & 255;
    wT[t] = f2b(ldp(Ws, i*32768 + k*128 + n, f32m));
  } else if (t < 589824) {             // WoT: [128][128]
    int u = t - 491520; int i = u >> 14; int rem = u & 16383; int n = rem >> 7; int k = rem & 127;
    wT[t] = f2b(ldp(Wo, i*16384 + k*128 + n, f32m));
  } else if (t < 606208) {             // WcT: [128][128]
    int u = t - 589824; int n = u >> 7; int k = u & 127;
    wT[t] = f2b(ldp(Wc, k*128 + n, f32m));
  }
}

// sorted ascending insert into (ld,li)[20], strict '<' keeps earliest index on ties
#define INS(act, dv, iv) do { bool A_ = (act); float D_ = (dv); int I_ = (iv);        \
  _Pragma("unroll")                                                                    \
  for (int j = 19; j >= 1; --j) {                                                      \
    bool cj = A_ && (D_ < ld[j]); bool cm = A_ && (D_ < ld[j-1]);                      \
    ld[j] = cj ? (cm ? ld[j-1] : D_) : ld[j];                                          \
    li[j] = cj ? (cm ? li[j-1] : I_) : li[j];                                          \
  }                                                                                    \
  { bool c0 = A_ && (D_ < ld[0]); ld[0] = c0 ? D_ : ld[0]; li[0] = c0 ? I_ : li[0]; } \
} while(0)

// ---------------- KNN: 4 waves/query-group, partitioned candidates ----------------
// R4/R6 proven structure + cross-partition shared threshold: sharedmin =
// min over partitions of ld[19] is a valid upper bound of the global 20th-best
// (each ld[19] >= partition-true-20th >= global-20th), maintained via LDS
// atomicMin on positive-float bits at each flush. Cuts admissions ~3x.
// Selected top-20 set/order provably unchanged for any thresh-update timing.
__global__ __launch_bounds__(256) void k_knn(const float4* __restrict__ pf4,
                                             const void* __restrict__ Wc,
                                             const void* __restrict__ bc,
                                             const int* __restrict__ flagp,
                                             unsigned short* __restrict__ idx16,
                                             unsigned short* __restrict__ wsoftb){
  __shared__ char smem[40960];
  __shared__ unsigned int sthr[64];             // per-query shared threshold (float bits)
  float4* tile = (float4*)smem;                 // [4][256] float4 = 16 KB (scan phase)
  float*  lsd  = (float*)smem;                  // [256][20] = 20 KB (merge phase)
  int*    lsi  = (int*)(smem + 20480);          // [256][20] = 20 KB

  int tid  = threadIdx.x;
  int part = tid >> 6, lane = tid & 63;
  int rq   = blockIdx.x*64 + lane;              // query row (512 blocks x 64)
  int b    = rq >> 12;
  int f32m = *flagp;
  float4 q = pf4[rq];

  if (tid < 64) sthr[tid] = 0x7F7FFFFFu;        // +3.4e38

  float ld[20]; int li[20];
  #pragma unroll
  for (int j = 0; j < 20; ++j) { ld[j] = 3.0e38f; li[j] = 0; }
  float thresh = 3.0e38f;
  float bd0=0.f,bd1=0.f,bd2=0.f,bd3=0.f; int bi0=0,bi1=0,bi2=0,bi3=0; int cnt=0;

  for (int ch = 0; ch < 4; ++ch) {
    __syncthreads();
    {
      const float4* src = pf4 + (b << 12) + part*1024 + ch*256;
      tile[part*256 + lane      ] = src[lane      ];
      tile[part*256 + lane +  64] = src[lane +  64];
      tile[part*256 + lane + 128] = src[lane + 128];
      tile[part*256 + lane + 192] = src[lane + 192];
    }
    __syncthreads();
    int baseI = part*1024 + ch*256;
    for (int j = 0; j < 256; ++j) {
      float4 pt = tile[part*256 + j];
      float dot = __fadd_rn(__fadd_rn(__fmul_rn(q.x,pt.x), __fmul_rn(q.y,pt.y)),
                            __fmul_rn(q.z,pt.z));
      float d2  = __fsub_rn(__fadd_rn(q.w, pt.w), __fmul_rn(2.0f, dot));
      bool take = d2 < thresh;       // thresh >= true global 20th-best at all times
      int  gi   = baseI + j;
      bool t0 = take && (cnt == 0); bd0 = t0 ? d2 : bd0; bi0 = t0 ? gi : bi0;
      bool t1 = take && (cnt == 1); bd1 = t1 ? d2 : bd1; bi1 = t1 ? gi : bi1;
      bool t2 = take && (cnt == 2); bd2 = t2 ? d2 : bd2; bi2 = t2 ? gi : bi2;
      bool t3 = take && (cnt == 3); bd3 = t3 ? d2 : bd3; bi3 = t3 ? gi : bi3;
      cnt += take ? 1 : 0;
      if (__ballot(cnt >= 4)) {      // wave-uniform branch
        INS(cnt > 0, bd0, bi0); INS(cnt > 1, bd1, bi1);
        INS(cnt > 2, bd2, bi2); INS(cnt > 3, bd3, bi3);
        cnt = 0;
        atomicMin(&sthr[lane], __float_as_uint(fmaxf(ld[19], 0.0f)));
        thresh = fminf(ld[19], __uint_as_float(sthr[lane]));
      }
    }
  }
  INS(cnt > 0, bd0, bi0); INS(cnt > 1, bd1, bi1);
  INS(cnt > 2, bd2, bi2); INS(cnt > 3, bd3, bi3);

  __syncthreads();                   // scan done; tile region reused as lsd/lsi
  #pragma unroll
  for (int j = 0; j < 20; ++j) { lsd[tid*20 + j] = ld[j]; lsi[tid*20 + j] = li[j]; }
  __syncthreads();

  if (tid < 64) {                    // lane q of wave 0 merges query q's 4 lists
    int p0 = tid*20, p1 = (64+tid)*20, p2 = (128+tid)*20, p3 = (192+tid)*20;
    int i0=0, i1=0, i2=0, i3=0;
    float dis[20]; int outi[20];
    #pragma unroll 4
    for (int o = 0; o < 20; ++o) {
      float d0 = lsd[p0+i0], d1 = lsd[p1+i1], d2v = lsd[p2+i2], d3 = lsd[p3+i3];
      float bd = d0; int sel = 0;
      if (d1  < bd) { bd = d1;  sel = 1; }    // strict <: lowest partition wins ties
      if (d2v < bd) { bd = d2v; sel = 2; }
      if (d3  < bd) { bd = d3;  sel = 3; }
      int bi = (sel==0) ? lsi[p0+i0] : (sel==1) ? lsi[p1+i1] : (sel==2) ? lsi[p2+i2] : lsi[p3+i3];
      i0 += (sel==0); i1 += (sel==1); i2 += (sel==2); i3 += (sel==3);
      dis[o] = sqrtf(fmaxf(bd, 1e-12f));
      outi[o] = bi;
    }
    // ---- fused attention softmax weights, all 6 blocks ----
    float nx[20], ny[20], nz[20];
    #pragma unroll 4
    for (int k = 0; k < 20; ++k) {
      idx16[rq*20 + k] = (unsigned short)outi[k];
      float4 pp = pf4[(b << 12) + outi[k]];
      nx[k] = pp.x; ny[k] = pp.y; nz[k] = pp.z;
    }
    for (int i = 0; i < NBK; ++i) {
      float w0 = ldp(Wc,i*7+0,f32m), w1 = ldp(Wc,i*7+1,f32m), w2 = ldp(Wc,i*7+2,f32m);
      float w3 = ldp(Wc,i*7+3,f32m), w4 = ldp(Wc,i*7+4,f32m), w5 = ldp(Wc,i*7+5,f32m);
      float w6 = ldp(Wc,i*7+6,f32m);
      float bci = ldp(bc,i,f32m);
      float s[20]; float mx = -3.0e38f;
      #pragma unroll
      for (int k = 0; k < 20; ++k) {
        float v = bci;
        v = fmaf(dis[k], w0, v);
        v = fmaf(nx[k], w1, v); v = fmaf(ny[k], w2, v); v = fmaf(nz[k], w3, v);
        v = fmaf(q.x, w4, v);  v = fmaf(q.y, w5, v);  v = fmaf(q.z, w6, v);
        s[k] = v; mx = fmaxf(mx, v);
      }
      float sum = 0.f;
      #pragma unroll
      for (int k = 0; k < 20; ++k) { float e = __expf(s[k] - mx); s[k] = e; sum += e; }
      float inv = 1.0f / sum;
      #pragma unroll
      for (int k = 0; k < 20; ++k) wsoftb[(rq*6 + i)*20 + k] = f2b(s[k]*inv);
    }
  }
}

// ---------------- one resnet block (fused gather+attention+GEMMs) ----------------
// R6 proven structure (1024 blocks x 32 rows, col-split, 4 barriers) + batched
// gather (R11, proven). Accumulation order identical to R6.
__global__ __launch_bounds__(256) void k_block(const unsigned short* __restrict__ netIn,
                                               unsigned short* __restrict__ netOut,
                                               const unsigned short* __restrict__ idx16,
                                               const unsigned short* __restrict__ wsoftb,
                                               const unsigned short* __restrict__ wT,
                                               const void* __restrict__ b0s,
                                               const void* __restrict__ b1s,
                                               const void* __restrict__ bos,
                                               const int* __restrict__ flagp,
                                               int iblk, int hasResid){
  __shared__ unsigned short ldsA[2][16*136];
  __shared__ unsigned short ldsH[2][16*136];
  int tid = threadIdx.x;
  int f32m = *flagp;
  int w = tid >> 6, lane = tid & 63;
  int t = w >> 1;            // row tile 0/1
  int c = w & 1;             // col half 0/1
  int b  = blockIdx.x & 7;   // XCD swizzle: gathers stay within one batch's net
  int r0 = (b << 12) + ((blockIdx.x >> 3) << 5) + (t << 4);
  const unsigned short* W0T = wT + iblk*32768;
  const unsigned short* W1T = wT + 196608 + iblk*16384;
  const unsigned short* WsT = wT + 294912 + iblk*32768;
  const unsigned short* WoT = wT + 491520 + iblk*16384;
  int m = lane & 15, qd = lane >> 4;

  // ---- stage 1: attsum[r][cols c*64+cg*16 .. +16] = sum_k w * netIn[idx_k] ----
  {
    int r = lane >> 2, cg = lane & 3;
    int grow = r0 + r;
    int cbase = c*64 + cg*16;
    const unsigned int* ip = (const unsigned int*)(idx16 + grow*20);
    const unsigned int* wp = (const unsigned int*)(wsoftb + (grow*6 + iblk)*20);
    unsigned int iv[10], wv[10];
    #pragma unroll
    for (int j = 0; j < 10; ++j) iv[j] = ip[j];
    #pragma unroll
    for (int j = 0; j < 10; ++j) wv[j] = wp[j];
    float acc[16];
    #pragma unroll
    for (int j = 0; j < 16; ++j) acc[j] = 0.f;
    #pragma unroll 4
    for (int k = 0; k < 20; ++k) {
      unsigned int pair = iv[k >> 1];
      int nb = (int)((k & 1) ? (pair >> 16) : pair) & 4095;
      unsigned int wpair = wv[k >> 1];
      float wk = (k & 1) ? hi2f(wpair) : lo2f(wpair);
      const uint4* np_ = (const uint4*)(netIn + ((b << 12) + nb)*128 + cbase);
      #pragma unroll
      for (int u = 0; u < 2; ++u) {
        uint4 uu = np_[u];
        acc[u*8+0] = fmaf(wk, lo2f(uu.x), acc[u*8+0]);
        acc[u*8+1] = fmaf(wk, hi2f(uu.x), acc[u*8+1]);
        acc[u*8+2] = fmaf(wk, lo2f(uu.y), acc[u*8+2]);
        acc[u*8+3] = fmaf(wk, hi2f(uu.y), acc[u*8+3]);
        acc[u*8+4] = fmaf(wk, lo2f(uu.z), acc[u*8+4]);
        acc[u*8+5] = fmaf(wk, hi2f(uu.z), acc[u*8+5]);
        acc[u*8+6] = fmaf(wk, lo2f(uu.w), acc[u*8+6]);
        acc[u*8+7] = fmaf(wk, hi2f(uu.w), acc[u*8+7]);
      }
    }
    unsigned short* hb = ldsH[t];
    #pragma unroll
    for (int j = 0; j < 8; ++j) {
      unsigned int pr = ((unsigned int)f2b(acc[2*j+1]) << 16) | (unsigned int)f2b(acc[2*j]);
      *(unsigned int*)(hb + r*136 + cbase + 2*j) = pr;
    }
  }
  __syncthreads();

  // ---- stage 2: att = attsum @ Wo^T + bo -> ldsA (4 col-tiles per wave) ----
  {
    bf16x8 asf[4];
    #pragma unroll
    for (int ks = 0; ks < 4; ++ks)
      asf[ks] = *(const bf16x8*)(ldsH[t] + m*136 + ks*32 + qd*8);
    f32x4 acc2[4];
    #pragma unroll
    for (int i = 0; i < 4; ++i) { f32x4 z = {0.f,0.f,0.f,0.f}; acc2[i] = z; }
    #pragma unroll
    for (int i = 0; i < 4; ++i) {
      int cti = c*4 + i;
      const unsigned short* bp = WoT + (cti*16 + m)*128 + qd*8;
      #pragma unroll
      for (int ks = 0; ks < 4; ++ks)
        acc2[i] = __builtin_amdgcn_mfma_f32_16x16x32_bf16(asf[ks], *(const bf16x8*)(bp + ks*32), acc2[i], 0, 0, 0);
    }
    unsigned short* ab = ldsA[t];
    #pragma unroll
    for (int i = 0; i < 4; ++i) {
      int col = (c*4 + i)*16 + m;
      float bo = ldp(bos, iblk*128 + col, f32m);
      #pragma unroll
      for (int rr = 0; rr < 4; ++rr)
        ab[(qd*4 + rr)*136 + col] = f2b(acc2[i][rr] + bo);
    }
  }
  __syncthreads();

  // ---- stage 3: h = relu(net)@W0a + relu(att)@W0b + b0; relu(h) -> ldsH ----
  bf16x8 nf[4], af[4];
  {
    const unsigned short* nrow = netIn + (r0 + m)*128;
    #pragma unroll
    for (int ks = 0; ks < 4; ++ks) nf[ks] = *(const bf16x8*)(nrow + ks*32 + qd*8);
    #pragma unroll
    for (int ks = 0; ks < 4; ++ks) af[ks] = *(const bf16x8*)(ldsA[t] + m*136 + ks*32 + qd*8);
    bf16x8 rnf[4], raf[4];
    #pragma unroll
    for (int ks = 0; ks < 4; ++ks) { rnf[ks] = relu8(nf[ks]); raf[ks] = relu8(af[ks]); }
    f32x4 acc3[4];
    #pragma unroll
    for (int i = 0; i < 4; ++i) { f32x4 z = {0.f,0.f,0.f,0.f}; acc3[i] = z; }
    #pragma unroll
    for (int i = 0; i < 4; ++i) {
      int cti = c*4 + i;
      const unsigned short* bp = W0T + (cti*16 + m)*256 + qd*8;
      #pragma unroll
      for (int ks = 0; ks < 4; ++ks)
        acc3[i] = __builtin_amdgcn_mfma_f32_16x16x32_bf16(rnf[ks], *(const bf16x8*)(bp + ks*32), acc3[i], 0, 0, 0);
      #pragma unroll
      for (int ks = 0; ks < 4; ++ks)
        acc3[i] = __builtin_amdgcn_mfma_f32_16x16x32_bf16(raf[ks], *(const bf16x8*)(bp + 128 + ks*32), acc3[i], 0, 0, 0);
    }
    unsigned short* hb = ldsH[t];
    #pragma unroll
    for (int i = 0; i < 4; ++i) {
      int col = (c*4 + i)*16 + m;
      float b0v = ldp(b0s, iblk*128 + col, f32m);
      #pragma unroll
      for (int rr = 0; rr < 4; ++rr)
        hb[(qd*4 + rr)*136 + col] = f2b(fmaxf(acc3[i][rr] + b0v, 0.f));
    }
  }
  __syncthreads();

  // ---- stage 4: out = relu(h)@W1 + b1 + net@Wsa + att@Wsb (+ resid) ----
  {
    bf16x8 hf[4];
    #pragma unroll
    for (int ks = 0; ks < 4; ++ks) hf[ks] = *(const bf16x8*)(ldsH[t] + m*136 + ks*32 + qd*8);
    f32x4 acc4[4];
    #pragma unroll
    for (int i = 0; i < 4; ++i) { f32x4 z = {0.f,0.f,0.f,0.f}; acc4[i] = z; }
    #pragma unroll
    for (int i = 0; i < 4; ++i) {
      int cti = c*4 + i;
      const unsigned short* bp1 = W1T + (cti*16 + m)*128 + qd*8;
      #pragma unroll
      for (int ks = 0; ks < 4; ++ks)
        acc4[i] = __builtin_amdgcn_mfma_f32_16x16x32_bf16(hf[ks], *(const bf16x8*)(bp1 + ks*32), acc4[i], 0, 0, 0);
      const unsigned short* bps = WsT + (cti*16 + m)*256 + qd*8;
      #pragma unroll
      for (int ks = 0; ks < 4; ++ks)
        acc4[i] = __builtin_amdgcn_mfma_f32_16x16x32_bf16(nf[ks], *(const bf16x8*)(bps + ks*32), acc4[i], 0, 0, 0);
      #pragma unroll
      for (int ks = 0; ks < 4; ++ks)
        acc4[i] = __builtin_amdgcn_mfma_f32_16x16x32_bf16(af[ks], *(const bf16x8*)(bps + 128 + ks*32), acc4[i], 0, 0, 0);
    }
    #pragma unroll
    for (int i = 0; i < 4; ++i) {
      int col = (c*4 + i)*16 + m;
      float b1v = ldp(b1s, iblk*128 + col, f32m);
      #pragma unroll
      for (int rr = 0; rr < 4; ++rr) {
        int grow2 = r0 + qd*4 + rr;
        float v = acc4[i][rr] + b1v;
        if (hasResid) v += b2f(netIn[grow2*128 + col]);
        netOut[grow2*128 + col] = f2b(v);
      }
    }
  }
}

// ---------------- final: out = net @ W_c + b_c (dtype per flag) ----------------
__global__ __launch_bounds__(256) void k_final(const unsigned short* __restrict__ netIn,
                                               const unsigned short* __restrict__ WcT,
                                               const void* __restrict__ bcv,
                                               const int* __restrict__ flagp,
                                               void* __restrict__ out){
  int tid = threadIdx.x; int w = tid >> 6, lane = tid & 63;
  int f32m = *flagp;
  int t = w >> 1, c = w & 1;
  int r0 = blockIdx.x*32 + t*16;
  int m = lane & 15, qd = lane >> 4;
  bf16x8 nf[4];
  #pragma unroll
  for (int ks = 0; ks < 4; ++ks)
    nf[ks] = *(const bf16x8*)(netIn + (r0 + m)*128 + ks*32 + qd*8);
  f32x4 acc[4];
  #pragma unroll
  for (int i = 0; i < 4; ++i) { f32x4 z = {0.f,0.f,0.f,0.f}; acc[i] = z; }
  #pragma unroll
  for (int i = 0; i < 4; ++i) {
    int cti = c*4 + i;
    const unsigned short* bp = WcT + (cti*16 + m)*128 + qd*8;
    #pragma unroll
    for (int ks = 0; ks < 4; ++ks)
      acc[i] = __builtin_amdgcn_mfma_f32_16x16x32_bf16(nf[ks], *(const bf16x8*)(bp + ks*32), acc[i], 0, 0, 0);
  }
  if (f32m) {
    float* o = (float*)out;
    #pragma unroll
    for (int i = 0; i < 4; ++i) {
      int col = (c*4 + i)*16 + m;
      float bcf = ldp(bcv, col, 1);
      #pragma unroll
      for (int rr = 0; rr < 4; ++rr)
        o[(r0 + qd*4 + rr)*128 + col] = acc[i][rr] + bcf;
    }
  } else {
    unsigned short* o = (unsigned short*)out;
    #pragma unroll
    for (int i = 0; i < 4; ++i) {
      int col = (c*4 + i)*16 + m;
      float bcf = ldp(bcv, col, 0);
      #pragma unroll
      for (int rr = 0; rr < 4; ++rr)
        o[(r0 + qd*4 + rr)*128 + col] = f2b(acc[i][rr] + bcf);
    }
  }
}

// ---------------- host launch ----------------
extern "C" void kernel_launch(void* const* d_in, const int* in_sizes, int n_in,
                              void* d_out, int out_size, void* d_ws, size_t ws_size,
                              hipStream_t stream){
  const void* p    = d_in[0];
  const void* Wpos = d_in[1];
  const void* bpos = d_in[2];
  const void* W0   = d_in[3];
  const void* b0   = d_in[4];
  const void* W1   = d_in[5];
  const void* b1   = d_in[6];
  const void* Ws   = d_in[7];
  const void* Wc_  = d_in[8];
  const void* bc_  = d_in[9];
  const void* Wo   = d_in[10];
  const void* bo   = d_in[11];
  const void* WC   = d_in[12];
  const void* bC   = d_in[13];

  char* ws = (char*)d_ws;
  int*            flag   = (int*)(ws + 0);                    //      256 B (padded)
  float4*         pf4    = (float4*)(ws + 256);               //   524288 B
  unsigned short* idx16  = (unsigned short*)(ws + 524544);    //  1310720 B
  unsigned short* wsoftb = (unsigned short*)(ws + 1835264);   //  7864320 B
  unsigned short* netA   = (unsigned short*)(ws + 9699584);   //  8388608 B
  unsigned short* wT     = (unsigned short*)(ws + 18088192);  //  1212416 B (total ~19.3 MB)

  k_detect     <<<dim3(1),     dim3(64),  0, stream>>>((const unsigned short*)Wpos, flag);
  k_prep_points<<<dim3(128),   dim3(256), 0, stream>>>(p, flag, pf4);
  k_net0       <<<dim3(16384), dim3(256), 0, stream>>>(pf4, Wpos, bpos, flag, netA);
  k_transpose  <<<dim3(2368),  dim3(256), 0, stream>>>(W0, W1, Ws, Wo, WC, flag, wT);
  k_knn        <<<dim3(512),   dim3(256), 0, stream>>>(pf4, Wc_, bc_, flag, idx16, wsoftb);

  unsigned short* a   = netA;
  unsigned short* bpt = (unsigned short*)d_out;   // d_out as bf16 ping-pong scratch
  for (int i = 0; i < 6; ++i) {
    k_block<<<dim3(1024), dim3(256), 0, stream>>>(a, bpt, idx16, wsoftb, wT,
                                                  b0, b1, bo, flag, i, (i > 0) ? 1 : 0);
    unsigned short* t = a; a = bpt; bpt = t;
  }
  // 6 swaps: final net is in netA (== a)
  k_final<<<dim3(1024), dim3(256), 0, stream>>>(a, wT + 589824, bC, flag, d_out);
}